// Round 8
// baseline (824.261 us; speedup 1.0000x reference)
//
#include <hip/hip_runtime.h>
#include <stdint.h>

// ---------------------------------------------------------------------------
// Net_52948356825721: 4x edge-conv GNN.
// R4: edge MLPs -> MFMA split-bf16 (hi/lo, 3 products): 1795 -> 969 us.
// R5: node GEMMs -> MFMA; staging bank swizzle: 969 -> 922 us.
// R6: Q2 fusion (conv2 K 704->64) + ex frag-order global scratch: 943 us.
// R7: LDS-free A-path + reg ping-pong: 896 us.
// R8: edge_c1 W dbuf LDS via global_load_lds + counted vmcnt: 843 us.
// R9: launch-graph consolidation 24 -> 11 dispatches: 820 us.
// R10: edge_lite 3 blocks/CU + Q2 lane-major layout: 821 us (neutral).
// R11: (a) edge_c1 -> 3 blocks/CU: HALF-STEP W staging (16KB kt-halves,
//      ring-2 = 32KB; wp2 staged once at start into its own 16KB slot ->
//      peak LDS 48KB+misc = 53.8KB); A-ring 3 half-bufs (48 VGPR);
//      vmcnt(8) steady / vmcnt(0) at last half-step. launch_bounds(256,3).
//      (b) edge_lite: P-gather prefetched into registers BEFORE the K-loop
//      (64 loads overlap the frag MFMAs; epilogue reads registers).
// k-slot bijection k = 4q + (r&3) + 16(r>>2) shared by A-frags and W packs.
// C/D: col = lane&15, row = 4*(lane>>4)+reg.
// ---------------------------------------------------------------------------

#define N_NODES 10000
#define N_EDGES 128000
#define E_HALF  64000
#define NBLK    1000          // 128-edge blocks

typedef unsigned short u16;

using bf16x8 = __attribute__((ext_vector_type(8))) short;
using f32x4  = __attribute__((ext_vector_type(4))) float;

#define MFMA16(A, B, C) C = __builtin_amdgcn_mfma_f32_16x16x32_bf16(A, B, C, 0, 0, 0)

__device__ __align__(256) float g_acc[N_NODES * 64];
__device__ __align__(256) float g_deg[N_NODES];
__device__ __align__(256) float g_P[N_NODES * 128];
__device__ __align__(256) float g_x1[N_NODES * 64];
__device__ __align__(256) float g_x2[N_NODES * 64];
__device__ __align__(256) float g_x3[N_NODES * 64];
__device__ __align__(256) u16  g_fragA[(size_t)NBLK * 16384];  // ex1, later ex3
__device__ __align__(256) u16  g_fragB[(size_t)NBLK * 16384];  // ex2
__device__ __align__(256) float g_Q2 [(size_t)NBLK * 8192];    // lane-major frag layout
__device__ __align__(256) float g_ex4[(size_t)N_EDGES * 64];   // conv4 out (f32)
__device__ __align__(256) u16  g_wpA_hi[5 * 4096];   // edge W1 packs: c2@0, c3@4096, c4@12288
__device__ __align__(256) u16  g_wpA_lo[5 * 4096];
__device__ __align__(256) u16  g_wp2_hi[4 * 4096];   // edge W2 packs: c1..c4
__device__ __align__(256) u16  g_wp2_lo[4 * 4096];
__device__ __align__(256) u16  g_wnp_hi[9 * 8192];   // node W packs: c1@0(4), c2@4, c3@5, c4@7
__device__ __align__(256) u16  g_wnp_lo[9 * 8192];
__device__ __align__(256) u16  g_wpC_hi[10 * 8192];  // conv1 combined pack (8-ct)
__device__ __align__(256) u16  g_wpC_lo[10 * 8192];
__device__ __align__(256) int g_row[N_EDGES];
__device__ __align__(256) int g_col[N_EDGES];
__device__ int g_mode;   // 0 = bf16 I/O, 1 = f32 I/O
__device__ int g_is64;   // edge_index is int64

__device__ __forceinline__ float b2f(u16 u) {
    return __uint_as_float(((unsigned int)u) << 16);
}
__device__ __forceinline__ u16 f2b(float f) {
    unsigned int u = __float_as_uint(f);
    u += 0x7FFFu + ((u >> 16) & 1u);   // RNE
    return (u16)(u >> 16);
}
__device__ __forceinline__ float ldf(const u16* p)   { return b2f(*p); }
__device__ __forceinline__ float ldf(const float* p) { return *p; }
__device__ __forceinline__ void  stf(u16* p, float v)   { *p = f2b(v); }
__device__ __forceinline__ void  stf(float* p, float v) { *p = v; }

__device__ __forceinline__ float4 load4(const float* p) { return *(const float4*)p; }
__device__ __forceinline__ float4 load4(const u16* p) {
    ushort4 v = *(const ushort4*)p;
    return make_float4(b2f(v.x), b2f(v.y), b2f(v.z), b2f(v.w));
}

// async global->LDS, 16B per lane: LDS dest = base + lane*16 (HW), src per-lane
__device__ __forceinline__ void gl_lds16(const void* g, void* l) {
    __builtin_amdgcn_global_load_lds(
        (const __attribute__((address_space(1))) void*)g,
        (__attribute__((address_space(3))) void*)l, 16, 0, 0);
}

// split 4 f32 into packed bf16 hi (truncation) + lo (RNE of exact residual)
__device__ __forceinline__ void split_pack(float4 v, uint2& hi, uint2& lo) {
    unsigned int ux = __float_as_uint(v.x), uy = __float_as_uint(v.y);
    unsigned int uz = __float_as_uint(v.z), uw = __float_as_uint(v.w);
    unsigned int hx = ux & 0xFFFF0000u, hy = uy & 0xFFFF0000u;
    unsigned int hz = uz & 0xFFFF0000u, hw = uw & 0xFFFF0000u;
    hi.x = (hx >> 16) | hy;
    hi.y = (hz >> 16) | hw;
    u16 lx = f2b(v.x - __uint_as_float(hx));
    u16 ly = f2b(v.y - __uint_as_float(hy));
    u16 lz = f2b(v.z - __uint_as_float(hz));
    u16 lw = f2b(v.w - __uint_as_float(hw));
    lo.x = (unsigned int)lx | ((unsigned int)ly << 16);
    lo.y = (unsigned int)lz | ((unsigned int)lw << 16);
}

// build A-fragment (hi/lo planes) from the two float4 halves:
// v0 -> frag words 0,1 (k = 4q+{0..3}); v1 -> words 2,3 (k = 4q+16+{0..3})
__device__ __forceinline__ void mk_frag(float4 v0, float4 v1,
                                        bf16x8& fh, bf16x8& fl) {
    uint2 h0, l0, h1, l1;
    split_pack(v0, h0, l0);
    split_pack(v1, h1, l1);
    union { unsigned int w[4]; bf16x8 v; } H, L;
    H.w[0] = h0.x; H.w[1] = h0.y; H.w[2] = h1.x; H.w[3] = h1.y;
    L.w[0] = l0.x; L.w[1] = l0.y; L.w[2] = l1.x; L.w[3] = l1.y;
    fh = H.v; fl = L.v;
}

// --- prologue A: zero acc/deg + dtype/idx-width detection -------------------
__global__ void prologue_a(const void* x_org_v, const int* __restrict__ eidx) {
    const int i = blockIdx.x * 256 + threadIdx.x;   // exact 2500*256 = 640000
    g_acc[i] = 0.f;
    if (i < N_NODES) g_deg[i] = 0.f;
    if (blockIdx.x == 0 && threadIdx.x < 64) {
        const u16* w = (const u16*)x_org_v;
        const int t = threadIdx.x;
        int ok = 0;
        for (int j = t; j < 128; j += 64) {
            u16 v = w[j];
            int ex = (v >> 7) & 0xFF;
            ok += ((ex >= 0x68 && ex <= 0x88) || ((v & 0x7FFFu) == 0)) ? 1 : 0;
        }
        #pragma unroll
        for (int off = 32; off >= 1; off >>= 1) ok += __shfl_xor(ok, off);
        bool allz = true;
        for (int j = t; j < 2048; j += 64) allz = allz && (eidx[2 * j + 1] == 0);
        unsigned long long m = __ballot(allz);
        if (t == 0) {
            g_mode = (ok >= 110) ? 0 : 1;
            g_is64 = (m == ~0ull) ? 1 : 0;
        }
    }
}

// --- weight pre-pack primitives ---------------------------------------------
__device__ __forceinline__ void pack_pair(u16* dh, u16* dl, float v) {
    const u16 hh = f2b(v);
    *dh = hh; *dl = f2b(v - b2f(hh));
}
// node pack (8-ct): rem in [0, ns*8192)
template<typename TW>
__device__ void pack_wnp(const TW* w, int hioff, int rem, u16* dh, u16* dl) {
    const int s = rem >> 13, kt = (rem >> 12) & 1, ct = (rem >> 9) & 7,
              l = (rem >> 3) & 63, r = rem & 7;
    const int k = s * 64 + kt * 32 + 4 * (l >> 4) + (r & 3) + 16 * (r >> 2);
    const int col = ct * 16 + (l & 15);
    const int row = (col < 64) ? k : (hioff + k);
    pack_pair(dh + rem, dl + rem, ldf(w + (size_t)row * 64 + (col & 63)));
}
// 4-ct pack with row offset we (wp2 = we 0, 1 step)
template<typename TW>
__device__ void pack_wpa(const TW* w, int we, int rem, u16* dh, u16* dl) {
    const int s = rem >> 12, kt = (rem >> 11) & 1, ct = (rem >> 9) & 3,
              l = (rem >> 3) & 63, r = rem & 7;
    const int k = s * 64 + kt * 32 + 4 * (l >> 4) + (r & 3) + 16 * (r >> 2);
    pack_pair(dh + rem, dl + rem,
              ldf(w + (size_t)(we + k) * 64 + ct * 16 + (l & 15)));
}
// conv1 combined 8-ct: cols 0-63 c1_w1[520+k], 64-127 c2_w1[128+k]
template<typename TW>
__device__ void pack_wpc(const TW* w1, const TW* w2w, int rem) {
    const int s = rem >> 13, kt = (rem >> 12) & 1, ct = (rem >> 9) & 7,
              l = (rem >> 3) & 63, r = rem & 7;
    const int k = s * 64 + kt * 32 + 4 * (l >> 4) + (r & 3) + 16 * (r >> 2);
    const int col = ct * 16 + (l & 15);
    float v = (col < 64) ? ldf(w1 + (size_t)(520 + k) * 64 + col)
                         : ldf(w2w + (size_t)(128 + k) * 64 + (col - 64));
    pack_pair(g_wpC_hi + rem, g_wpC_lo + rem, v);
}

template<typename TW>
__device__ void pack_all_body(const TW* c1w1, const TW* c1w2, const TW* c2w1,
        const TW* c2w2, const TW* c3w1, const TW* c3w2, const TW* c4w1,
        const TW* c4w2) {
    const int idx = blockIdx.x * 256 + threadIdx.x;
    if (idx < 81920)        pack_wpc<TW>(c1w1, c2w1, idx);
    else if (idx < 114688)  pack_wnp<TW>(c1w1, 260, idx - 81920,  g_wnp_hi,            g_wnp_lo);
    else if (idx < 122880)  pack_wnp<TW>(c2w1, 64,  idx - 114688, g_wnp_hi + 4 * 8192, g_wnp_lo + 4 * 8192);
    else if (idx < 139264)  pack_wnp<TW>(c3w1, 128, idx - 122880, g_wnp_hi + 5 * 8192, g_wnp_lo + 5 * 8192);
    else if (idx < 155648)  pack_wnp<TW>(c4w1, 128, idx - 139264, g_wnp_hi + 7 * 8192, g_wnp_lo + 7 * 8192);
    else if (idx < 159744)  pack_wpa<TW>(c2w1, 768, idx - 155648, g_wpA_hi,            g_wpA_lo);
    else if (idx < 167936)  pack_wpa<TW>(c3w1, 256, idx - 159744, g_wpA_hi + 4096,     g_wpA_lo + 4096);
    else if (idx < 176128)  pack_wpa<TW>(c4w1, 256, idx - 167936, g_wpA_hi + 12288,    g_wpA_lo + 12288);
    else if (idx < 180224)  pack_wpa<TW>(c1w2, 0,   idx - 176128, g_wp2_hi,            g_wp2_lo);
    else if (idx < 184320)  pack_wpa<TW>(c2w2, 0,   idx - 180224, g_wp2_hi + 4096,     g_wp2_lo + 4096);
    else if (idx < 188416)  pack_wpa<TW>(c3w2, 0,   idx - 184320, g_wp2_hi + 8192,     g_wp2_lo + 8192);
    else if (idx < 192512)  pack_wpa<TW>(c4w2, 0,   idx - 188416, g_wp2_hi + 12288,    g_wp2_lo + 12288);
}

// --- prep: blocks [0,752) pack all weights; [752,1252) idx convert + degree -
__global__ void prep_k(const void* c1w1, const void* c1w2, const void* c2w1,
        const void* c2w2, const void* c3w1, const void* c3w2, const void* c4w1,
        const void* c4w2, const int* __restrict__ eidx) {
    if ((int)blockIdx.x < 752) {
        if (g_mode == 0)
            pack_all_body<u16>((const u16*)c1w1, (const u16*)c1w2, (const u16*)c2w1,
                (const u16*)c2w2, (const u16*)c3w1, (const u16*)c3w2,
                (const u16*)c4w1, (const u16*)c4w2);
        else
            pack_all_body<float>((const float*)c1w1, (const float*)c1w2,
                (const float*)c2w1, (const float*)c2w2, (const float*)c3w1,
                (const float*)c3w2, (const float*)c4w1, (const float*)c4w2);
    } else {
        const int e = ((int)blockIdx.x - 752) * 256 + threadIdx.x;  // 500*256
        int row, col;
        if (g_is64) { row = eidx[2 * e]; col = eidx[2 * (e + N_EDGES)]; }
        else        { row = eidx[e];     col = eidx[e + N_EDGES]; }
        g_row[e] = row; g_col[e] = col;
        atomicAdd(&g_deg[row], 1.0f);
    }
}

// --- conv1 node GEMM: P = [x_org|x_rot] @ [W_r|W_c] (K=260, rot VALU tail) --
template<typename TA>
__device__ void node_mfma_in_body(float* smrot, float* smwt,
        const TA* A1, const TA* rotsrc, const TA* w1, float* P) {
    const int t = threadIdx.x;
    const int lane = t & 63, wid = t >> 6;
    const int q = lane >> 4, n = lane & 15;
    const int r0b = blockIdx.x * 64;

    if (t < 64) {
        const int rr = min(r0b + t, N_NODES - 1);
        float4 v = load4(rotsrc + (size_t)rr * 4);
        smrot[t * 4 + 0] = v.x; smrot[t * 4 + 1] = v.y;
        smrot[t * 4 + 2] = v.z; smrot[t * 4 + 3] = v.w;
    }
    for (int i = t; i < 512; i += 256) {
        const int j = i >> 7, c = i & 127;
        const int row = (c < 64) ? (256 + j) : (516 + j);
        smwt[i] = ldf(w1 + (size_t)row * 64 + (c & 63));
    }
    __syncthreads();

    const int arow = min(r0b + wid * 16 + n, N_NODES - 1);

    f32x4 acc[8];
    #pragma unroll
    for (int ct = 0; ct < 8; ++ct) acc[ct] = (f32x4){0.f, 0.f, 0.f, 0.f};

    #pragma unroll
    for (int s = 0; s < 4; ++s) {
        #pragma unroll
        for (int kt = 0; kt < 2; ++kt) {
            const TA* p = A1 + (size_t)arow * 256 + s * 64 + kt * 32 + q * 4;
            float4 v0 = load4(p), v1 = load4(p + 16);
            bf16x8 ah, al;
            mk_frag(v0, v1, ah, al);
            const u16* wph = g_wnp_hi + s * 8192;
            const u16* wpl = g_wnp_lo + s * 8192;
            #pragma unroll
            for (int ct = 0; ct < 8; ++ct) {
                bf16x8 bh = *(const bf16x8*)&wph[(kt * 8 + ct) * 512 + lane * 8];
                bf16x8 bl = *(const bf16x8*)&wpl[(kt * 8 + ct) * 512 + lane * 8];
                MFMA16(ah, bh, acc[ct]);
                MFMA16(al, bh, acc[ct]);
                MFMA16(ah, bl, acc[ct]);
            }
        }
    }

    #pragma unroll
    for (int ct = 0; ct < 8; ++ct) {
        #pragma unroll
        for (int i = 0; i < 4; ++i) {
            const int rl = wid * 16 + 4 * q + i;
            const int row = r0b + rl;
            const int col = ct * 16 + n;
            float v = acc[ct][i]
                    + smrot[rl * 4 + 0] * smwt[0 * 128 + col]
                    + smrot[rl * 4 + 1] * smwt[1 * 128 + col]
                    + smrot[rl * 4 + 2] * smwt[2 * 128 + col]
                    + smrot[rl * 4 + 3] * smwt[3 * 128 + col];
            if (row < N_NODES) P[(size_t)row * 128 + col] = v;
        }
    }
}

__global__ void __launch_bounds__(256) node_mfma_in(
        const void* A1, const void* rotsrc, const void* w1, float* __restrict__ P) {
    __shared__ float smrot[256], smwt[512];
    if (g_mode == 0)
        node_mfma_in_body<u16>(smrot, smwt, (const u16*)A1, (const u16*)rotsrc,
                               (const u16*)w1, P);
    else
        node_mfma_in_body<float>(smrot, smwt, (const float*)A1, (const float*)rotsrc,
                               (const float*)w1, P);
}

// --- convs 2-4 node GEMM with FUSED finalize: A1 = [relu](acc/deg) ----------
template<int NS2, bool RELU>
__global__ void __launch_bounds__(256) node_mfma_acc(
        const float* A2, float* __restrict__ xout, float* __restrict__ P,
        int wnpoff) {
    const int t = threadIdx.x;
    const int lane = t & 63, wid = t >> 6;
    const int q = lane >> 4, n = lane & 15;
    const int r0b = blockIdx.x * 64;
    const int rown = r0b + wid * 16 + n;
    const int arow = min(rown, N_NODES - 1);
    const bool own = rown < N_NODES;
    const float inv = 1.0f / fmaxf(g_deg[arow], 1.0f);

    f32x4 acc[8];
    #pragma unroll
    for (int ct = 0; ct < 8; ++ct) acc[ct] = (f32x4){0.f, 0.f, 0.f, 0.f};

    // s = 0: A from g_acc
    #pragma unroll
    for (int kt = 0; kt < 2; ++kt) {
        float* p = g_acc + (size_t)arow * 64 + kt * 32 + q * 4;
        float4 v0 = load4(p), v1 = load4(p + 16);
        v0.x *= inv; v0.y *= inv; v0.z *= inv; v0.w *= inv;
        v1.x *= inv; v1.y *= inv; v1.z *= inv; v1.w *= inv;
        if (RELU) {
            v0.x = fmaxf(v0.x, 0.f); v0.y = fmaxf(v0.y, 0.f);
            v0.z = fmaxf(v0.z, 0.f); v0.w = fmaxf(v0.w, 0.f);
            v1.x = fmaxf(v1.x, 0.f); v1.y = fmaxf(v1.y, 0.f);
            v1.z = fmaxf(v1.z, 0.f); v1.w = fmaxf(v1.w, 0.f);
        }
        if (own) {   // clamped dup lanes must not write (read-after-zero race)
            *(float4*)(xout + (size_t)arow * 64 + kt * 32 + q * 4) = v0;
            *(float4*)(xout + (size_t)arow * 64 + kt * 32 + q * 4 + 16) = v1;
            *(float4*)p = make_float4(0.f, 0.f, 0.f, 0.f);
            *(float4*)(p + 16) = make_float4(0.f, 0.f, 0.f, 0.f);
        }
        bf16x8 ah, al;
        mk_frag(v0, v1, ah, al);
        const u16* wph = g_wnp_hi + wnpoff;
        const u16* wpl = g_wnp_lo + wnpoff;
        #pragma unroll
        for (int ct = 0; ct < 8; ++ct) {
            bf16x8 bh = *(const bf16x8*)&wph[(kt * 8 + ct) * 512 + lane * 8];
            bf16x8 bl = *(const bf16x8*)&wpl[(kt * 8 + ct) * 512 + lane * 8];
            MFMA16(ah, bh, acc[ct]);
            MFMA16(al, bh, acc[ct]);
            MFMA16(ah, bl, acc[ct]);
        }
    }
    if constexpr (NS2 > 0) {   // s = 1: A from previous conv's x (materialized)
        #pragma unroll
        for (int kt = 0; kt < 2; ++kt) {
            const float* p = A2 + (size_t)arow * 64 + kt * 32 + q * 4;
            float4 v0 = load4(p), v1 = load4(p + 16);
            bf16x8 ah, al;
            mk_frag(v0, v1, ah, al);
            const u16* wph = g_wnp_hi + wnpoff + 8192;
            const u16* wpl = g_wnp_lo + wnpoff + 8192;
            #pragma unroll
            for (int ct = 0; ct < 8; ++ct) {
                bf16x8 bh = *(const bf16x8*)&wph[(kt * 8 + ct) * 512 + lane * 8];
                bf16x8 bl = *(const bf16x8*)&wpl[(kt * 8 + ct) * 512 + lane * 8];
                MFMA16(ah, bh, acc[ct]);
                MFMA16(al, bh, acc[ct]);
                MFMA16(ah, bl, acc[ct]);
            }
        }
    }

    #pragma unroll
    for (int ct = 0; ct < 8; ++ct) {
        #pragma unroll
        for (int i = 0; i < 4; ++i) {
            const int rl = wid * 16 + 4 * q + i;
            const int row = r0b + rl;
            if (row < N_NODES) P[(size_t)row * 128 + ct * 16 + n] = acc[ct][i];
        }
    }
}

// --- o-frag repack via wave LDS region + coalesced global store -------------
__device__ __forceinline__ void frag_store_o(u16* hreg, int wid, int lane,
        const f32x4 (&oacc)[2][4], u16* Fdst, int blkid) {
    const int q = lane >> 4, n = lane & 15;
    #pragma unroll
    for (int rt = 0; rt < 2; ++rt)
        #pragma unroll
        for (int ct = 0; ct < 4; ++ct)
            #pragma unroll
            for (int i = 0; i < 4; ++i) {
                float v = fmaxf(oacc[rt][ct][i], 0.f);   // relu'd edge feature
                unsigned int hb = __float_as_uint(v) & 0xFFFF0000u;
                const u16 hh = (u16)(hb >> 16);
                const u16 hl = f2b(v - __uint_as_float(hb));
                const int off = wid * 4096
                              + (((ct >> 1) * 2 + rt) * 64 + (n >> 2) * 16 + 4 * q + i) * 8
                              + (ct & 1) * 4 + (n & 3);
                hreg[off]        = hh;
                hreg[off + 2048] = hl;
            }
    #pragma unroll
    for (int kt = 0; kt < 2; ++kt)
        #pragma unroll
        for (int rtl = 0; rtl < 2; ++rtl) {
            const int src = wid * 4096 + ((kt * 2 + rtl) * 64 + lane) * 8;
            bf16x8 h8 = *(const bf16x8*)&hreg[src];
            bf16x8 l8 = *(const bf16x8*)&hreg[src + 2048];
            const size_t gb = (size_t)blkid * 16384
                            + (size_t)(kt * 8 + wid * 2 + rtl) * 512 + lane * 8;
            *(bf16x8*)&Fdst[gb]        = h8;
            *(bf16x8*)&Fdst[gb + 8192] = l8;
        }
}

// --- conv1 fused: h1 path + Q2 = edge_attr @ c2_w1[128:768] -----------------
// R11: half-step W staging. smW byte layout:
//   [0,16K)  half-step buf0   [16K,32K) half-step buf1   [32K,48K) wp2
//   each half-buf: hi [0,8K) + lo [8K,16K); half h -> buf (h&1), h = s*2+kt.
// wp2 staged ONCE at start (oldest in vmcnt queue, drains first).
// After the K loop: hreg (32KB) overlays [0,32K).
// A 3-deep half-step register ring (12 float4). launch_bounds(256,3).
template<typename TA, typename TW>
__device__ void edge_c1_body(u16* smW, int* srow, int* scol,
        float* b1s, float* b2s, float* rot, float* wtl,
        const TA* efa, const TA* rotsrc,
        const TW* w1, const TW* b1v, const TW* b2v) {
    const int t = threadIdx.x;
    const int lane = t & 63, wid = t >> 6;
    const int q = lane >> 4, n = lane & 15;
    const int e0 = blockIdx.x * 128;

    // stage wp2 once into bytes [32768, 49152)
    #pragma unroll
    for (int i = 0; i < 4; ++i) {
        const int L = wid * 4096 + i * 1024;
        const char* src = (L < 8192) ? (const char*)g_wp2_hi + L
                                     : (const char*)g_wp2_lo + (L - 8192);
        gl_lds16(src + lane * 16, (char*)smW + 32768 + L);
    }

    if (t < 128) srow[t] = g_row[e0 + t];
    else         scol[t - 128] = g_col[e0 + t - 128];
    if (t >= 128 && t < 192) b1s[t - 128] = ldf(b1v + (t - 128));
    if (t >= 192)            b2s[t - 192] = ldf(b2v + (t - 192));
    if (t < 128) {
        float4 r4 = load4(rotsrc + (size_t)(e0 + t) * 4);
        rot[t * 4 + 0] = r4.x; rot[t * 4 + 1] = r4.y;
        rot[t * 4 + 2] = r4.z; rot[t * 4 + 3] = r4.w;
    }
    wtl[t] = ldf(w1 + (size_t)(1160 + (t >> 6)) * 64 + (t & 63));

    const TA* arow0 = efa + (size_t)(e0 + wid * 32 + n) * 640;
    const TA* arow1 = efa + (size_t)(e0 + wid * 32 + 16 + n) * 640;

    f32x4 acc[2][8];
    #pragma unroll
    for (int a_ = 0; a_ < 2; ++a_)
        #pragma unroll
        for (int b_ = 0; b_ < 8; ++b_)
            acc[a_][b_] = (f32x4){0.f, 0.f, 0.f, 0.f};

    // stage 16KB half-step h -> LDS buf (h&1). per wave: 2KB hi + 2KB lo.
    auto stageW = [&](int h) {
        const char* sh = (const char*)g_wpC_hi + (size_t)h * 8192;
        const char* sl = (const char*)g_wpC_lo + (size_t)h * 8192;
        char* d = (char*)smW + (h & 1) * 16384;
        #pragma unroll
        for (int i = 0; i < 2; ++i) {
            const int off = wid * 2048 + i * 1024;
            gl_lds16(sh + off + lane * 16, d + off);
            gl_lds16(sl + off + lane * 16, d + 8192 + off);
        }
    };

    float4 abuf[3][2][2];
    auto issueA = [&](float4 (&buf)[2][2], int h) {   // 4 load4
        const int cb = (h >> 1) * 64 + (h & 1) * 32 + q * 4;
        buf[0][0] = load4(arow0 + cb);
        buf[0][1] = load4(arow0 + cb + 16);
        buf[1][0] = load4(arow1 + cb);
        buf[1][1] = load4(arow1 + cb + 16);
    };
    auto step = [&](float4 (&buf)[2][2], int h) {     // 48 MFMA
        const int wb = (h & 1) * 8192;                // u16 base of buf
        bf16x8 ah0, al0, ah1, al1;
        mk_frag(buf[0][0], buf[0][1], ah0, al0);
        mk_frag(buf[1][0], buf[1][1], ah1, al1);
        #pragma unroll
        for (int ct = 0; ct < 8; ++ct) {
            bf16x8 bh = *(const bf16x8*)&smW[wb + ct * 512 + lane * 8];
            bf16x8 bl = *(const bf16x8*)&smW[wb + 4096 + ct * 512 + lane * 8];
            MFMA16(ah0, bh, acc[0][ct]);
            MFMA16(ah1, bh, acc[1][ct]);
            MFMA16(al0, bh, acc[0][ct]);
            MFMA16(al1, bh, acc[1][ct]);
            MFMA16(ah0, bl, acc[0][ct]);
            MFMA16(ah1, bl, acc[1][ct]);
        }
    };

    // prologue: wp2(4) + W0(4) + A0(4) + A1(4) in flight; drain wp2+W0,
    // keep A0+A1 outstanding -> vmcnt(8).
    stageW(0);
    issueA(abuf[0], 0);
    issueA(abuf[1], 1);
    __builtin_amdgcn_sched_barrier(0);
    asm volatile("s_waitcnt vmcnt(8) lgkmcnt(0)");
    __builtin_amdgcn_sched_barrier(0);
    __builtin_amdgcn_s_barrier();

    // steady state at the wait: outstanding = stage(h+1)4 + A(h+1)4 -> vmcnt(8)
    // guarantees W(h) landed. h=19: full drain (also completes wp2).
    #pragma unroll
    for (int h = 0; h < 20; ++h) {
        if (h < 19) stageW(h + 1);
        __builtin_amdgcn_sched_barrier(0);
        if (h == 19) asm volatile("s_waitcnt vmcnt(0)");
        else         asm volatile("s_waitcnt vmcnt(8)");
        __builtin_amdgcn_sched_barrier(0);
        __builtin_amdgcn_s_barrier();          // W(h) visible to all waves
        if (h < 18) issueA(abuf[(h + 2) % 3], h + 2);
        step(abuf[h % 3], h);
        __builtin_amdgcn_s_barrier();          // buf(h&1) free for overwrite
    }
    // after the final barrier: all waves done reading W bufs; wp2 landed and
    // visible (drained before barrier1 of h=19).

    // ---- Q2 store (ct 4-7): lane-major frag layout, f32x4 stores
    {
        float* qf = g_Q2 + (size_t)blockIdx.x * 8192 + (size_t)t * 32;
        #pragma unroll
        for (int rt = 0; rt < 2; ++rt)
            #pragma unroll
            for (int c2 = 0; c2 < 4; ++c2)
                *(f32x4*)(qf + rt * 16 + c2 * 4) = acc[rt][4 + c2];
    }

    // ---- h = relu(acc + b1 + P_r + P_c + rot tail) -> frag LDS (overlay)
    u16* hreg = smW;
    #pragma unroll
    for (int rt = 0; rt < 2; ++rt)
        #pragma unroll
        for (int ct = 0; ct < 4; ++ct)
            #pragma unroll
            for (int i = 0; i < 4; ++i) {
                const int rl = wid * 32 + rt * 16 + 4 * q + i;
                const int col = ct * 16 + n;
                float v = acc[rt][ct][i] + b1s[col]
                        + g_P[(size_t)srow[rl] * 128 + col]
                        + g_P[(size_t)scol[rl] * 128 + 64 + col]
                        + rot[rl * 4 + 0] * wtl[0 * 64 + col]
                        + rot[rl * 4 + 1] * wtl[1 * 64 + col]
                        + rot[rl * 4 + 2] * wtl[2 * 64 + col]
                        + rot[rl * 4 + 3] * wtl[3 * 64 + col];
                v = fmaxf(v, 0.f);
                unsigned int hb = __float_as_uint(v) & 0xFFFF0000u;
                const u16 hh = (u16)(hb >> 16);
                const u16 hl = f2b(v - __uint_as_float(hb));
                const int off = wid * 4096
                              + (((ct >> 1) * 2 + rt) * 64 + (n >> 2) * 16 + 4 * q + i) * 8
                              + (ct & 1) * 4 + (n & 3);
                hreg[off]        = hh;
                hreg[off + 2048] = hl;
            }

    // ---- second GEMM: o = h @ w2 + b2 (w2 in LDS at u16 16384 hi / 20480 lo)
    f32x4 oacc[2][4];
    #pragma unroll
    for (int rt = 0; rt < 2; ++rt)
        #pragma unroll
        for (int ct = 0; ct < 4; ++ct) {
            const float bb = b2s[ct * 16 + n];
            oacc[rt][ct] = (f32x4){bb, bb, bb, bb};
        }
    #pragma unroll
    for (int kt = 0; kt < 2; ++kt) {
        const int r0 = wid * 4096 + ((kt * 2 + 0) * 64 + lane) * 8;
        const int r1 = wid * 4096 + ((kt * 2 + 1) * 64 + lane) * 8;
        bf16x8 ah0 = *(const bf16x8*)&hreg[r0];
        bf16x8 ah1 = *(const bf16x8*)&hreg[r1];
        bf16x8 al0 = *(const bf16x8*)&hreg[r0 + 2048];
        bf16x8 al1 = *(const bf16x8*)&hreg[r1 + 2048];
        #pragma unroll
        for (int ct = 0; ct < 4; ++ct) {
            bf16x8 bh = *(const bf16x8*)&smW[16384 + (kt * 4 + ct) * 512 + lane * 8];
            bf16x8 bl = *(const bf16x8*)&smW[20480 + (kt * 4 + ct) * 512 + lane * 8];
            MFMA16(ah0, bh, oacc[0][ct]);
            MFMA16(ah1, bh, oacc[1][ct]);
            MFMA16(al0, bh, oacc[0][ct]);
            MFMA16(al1, bh, oacc[1][ct]);
            MFMA16(ah0, bl, oacc[0][ct]);
            MFMA16(ah1, bl, oacc[1][ct]);
        }
    }

    // ---- scatter (pre-relu) + frag-store ex1
    #pragma unroll
    for (int rt = 0; rt < 2; ++rt)
        #pragma unroll
        for (int ct = 0; ct < 4; ++ct)
            #pragma unroll
            for (int i = 0; i < 4; ++i) {
                const int rl = wid * 32 + rt * 16 + 4 * q + i;
                atomicAdd(&g_acc[(size_t)srow[rl] * 64 + ct * 16 + n], oacc[rt][ct][i]);
            }
    frag_store_o(hreg, wid, lane, oacc, g_fragA, blockIdx.x);
}

__global__ void __launch_bounds__(256, 3) edge_c1(
        const void* efa, const void* rotsrc,
        const void* w1, const void* b1, const void* b2) {
    __shared__ __align__(16) u16 smW[24576];   // 48 KB
    __shared__ int srow[128], scol[128];
    __shared__ float b1s[64], b2s[64], rot[512], wtl[256];
    if (g_mode == 0)
        edge_c1_body<u16, u16>(smW, srow, scol, b1s, b2s, rot, wtl,
            (const u16*)efa, (const u16*)rotsrc,
            (const u16*)w1, (const u16*)b1, (const u16*)b2);
    else
        edge_c1_body<float, float>(smW, srow, scol, b1s, b2s, rot, wtl,
            (const float*)efa, (const float*)rotsrc,
            (const float*)w1, (const float*)b1, (const float*)b2);
}

// --- conv2/3/4: A from global frag buffers; W staged ONCE to LDS ------------
// Unified 48KB smW layout: [hreg 32KB (wpA overlaid at [0,NSF*16KB))]
// [wp2 16KB at byte 32768]. hreg reuses wpA after the post-K-loop barrier.
// R11: P-gather prefetched into registers before the K-loop.
template<typename TW, int NSF, bool HASQ2, bool FRAG_OUT>
__device__ void edge_lite_body(u16* smW, int* srow, int* scol,
        float* b1s, float* b2s,
        const u16* f0, const u16* f1,
        const TW* b1v, const TW* b2v, u16* Ffrag, float* fout,
        int wpAoff, int wp2off) {
    const int t = threadIdx.x;
    const int lane = t & 63, wid = t >> 6;
    const int q = lane >> 4, n = lane & 15;
    const int e0 = blockIdx.x * 128;
    const size_t blkb = (size_t)blockIdx.x * 16384;
    constexpr int N2 = 16384;                   // u16 offset of wp2_hi in smW

    // stage wpA -> bytes [0, NSF*16K), wp2 -> bytes [32K, 48K)
    #pragma unroll
    for (int i = 0; i < (NSF + 1) * 4; ++i) {
        const int j = i * 4 + wid;              // 1KB chunk id
        const char* src;
        int dstB;
        if (j < NSF * 8) {
            src = (const char*)(g_wpA_hi + wpAoff) + j * 1024;            dstB = j * 1024;
        } else if (j < NSF * 16) {
            src = (const char*)(g_wpA_lo + wpAoff) + (j - NSF * 8) * 1024; dstB = j * 1024;
        } else if (j < NSF * 16 + 8) {
            src = (const char*)(g_wp2_hi + wp2off) + (j - NSF * 16) * 1024;
            dstB = 32768 + (j - NSF * 16) * 1024;
        } else {
            src = (const char*)(g_wp2_lo + wp2off) + (j - NSF * 16 - 8) * 1024;
            dstB = 32768 + (j - NSF * 16) * 1024;
        }
        gl_lds16(src + lane * 16, (char*)smW + dstB);
    }

    if (t < 128) srow[t] = g_row[e0 + t];
    else         scol[t - 128] = g_col[e0 + t - 128];
    if (t >= 128 && t < 192) b1s[t - 128] = ldf(b1v + (t - 128));
    if (t >= 192)            b2s[t - 192] = ldf(b2v + (t - 192));
    __syncthreads();          // drains staging (vmcnt0) + prologue, one-time

    // ---- prefetch P-gather into registers (overlaps the frag K-loop)
    float pr[2][4][4], pc[2][4][4];
    #pragma unroll
    for (int rt = 0; rt < 2; ++rt)
        #pragma unroll
        for (int ct = 0; ct < 4; ++ct)
            #pragma unroll
            for (int i = 0; i < 4; ++i) {
                const int rl = wid * 32 + rt * 16 + 4 * q + i;
                const int col = ct * 16 + n;
                pr[rt][ct][i] = g_P[(size_t)srow[rl] * 128 + col];
                pc[rt][ct][i] = g_P[(size_t)scol[rl] * 128 + 64 + col];
            }

    f32x4 acc[2][4];
    #pragma unroll
    for (int a_ = 0; a_ < 2; ++a_)
        #pragma unroll
        for (int b_ = 0; b_ < 4; ++b_)
            acc[a_][b_] = (f32x4){0.f, 0.f, 0.f, 0.f};

    #pragma unroll
    for (int s = 0; s < NSF; ++s) {
        const u16* fs = (s == 0) ? f0 : f1;
        #pragma unroll
        for (int kt = 0; kt < 2; ++kt) {
            const size_t ba0 = blkb + (size_t)(kt * 8 + wid * 2 + 0) * 512 + lane * 8;
            const size_t ba1 = blkb + (size_t)(kt * 8 + wid * 2 + 1) * 512 + lane * 8;
            bf16x8 ah0 = *(const bf16x8*)&fs[ba0];
            bf16x8 al0 = *(const bf16x8*)&fs[ba0 + 8192];
            bf16x8 ah1 = *(const bf16x8*)&fs[ba1];
            bf16x8 al1 = *(const bf16x8*)&fs[ba1 + 8192];
            #pragma unroll
            for (int ct = 0; ct < 4; ++ct) {
                bf16x8 bh = *(const bf16x8*)&smW[s * 4096 + (kt * 4 + ct) * 512 + lane * 8];
                bf16x8 bl = *(const bf16x8*)&smW[NSF * 4096 + s * 4096 + (kt * 4 + ct) * 512 + lane * 8];
                MFMA16(ah0, bh, acc[0][ct]);
                MFMA16(ah1, bh, acc[1][ct]);
                MFMA16(al0, bh, acc[0][ct]);
                MFMA16(al1, bh, acc[1][ct]);
                MFMA16(ah0, bl, acc[0][ct]);
                MFMA16(ah1, bl, acc[1][ct]);
            }
        }
    }

    __builtin_amdgcn_s_barrier();   // all waves done reading wpA (hreg reuses it)
    u16* hreg = smW;

    const float* qf = g_Q2 + (size_t)blockIdx.x * 8192 + (size_t)t * 32;
    #pragma unroll
    for (int rt = 0; rt < 2; ++rt)
        #pragma unroll
        for (int ct = 0; ct < 4; ++ct) {
            f32x4 qv;
            if constexpr (HASQ2) qv = *(const f32x4*)(qf + rt * 16 + ct * 4);
            #pragma unroll
            for (int i = 0; i < 4; ++i) {
                const int rl = wid * 32 + rt * 16 + 4 * q + i;
                const int col = ct * 16 + n;
                float v = acc[rt][ct][i] + b1s[col]
                        + pr[rt][ct][i] + pc[rt][ct][i];
                if constexpr (HASQ2) v += qv[i];
                v = fmaxf(v, 0.f);
                unsigned int hb = __float_as_uint(v) & 0xFFFF0000u;
                const u16 hh = (u16)(hb >> 16);
                const u16 hl = f2b(v - __uint_as_float(hb));
                const int off = wid * 4096
                              + (((ct >> 1) * 2 + rt) * 64 + (n >> 2) * 16 + 4 * q + i) * 8
                              + (ct & 1) * 4 + (n & 3);
                hreg[off]        = hh;
                hreg[off + 2048] = hl;
            }
        }

    f32x4 oacc[2][4];
    #pragma unroll
    for (int rt = 0; rt < 2; ++rt)
        #pragma unroll
        for (int ct = 0; ct < 4; ++ct) {
            const float bb = b2s[ct * 16 + n];
            oacc[rt][ct] = (f32x4){bb, bb, bb, bb};
        }
    #pragma unroll
    for (int kt = 0; kt < 2; ++kt) {
        const int r0 = wid * 4096 + ((kt * 2 + 0) * 64 + lane) * 8;
        const int r1 = wid * 4096 + ((kt * 2 + 1) * 64 + lane) * 8;
        bf16x8 ah0 = *(const bf16x8*)&hreg[r0];
        bf16x8 ah1 = *(const bf16x8*)&hreg[r1];
        bf16x8 al0 = *(const bf16x8*)&hreg[r0 + 2048];
        bf16x8 al1 = *(const bf16x8*)&hreg[r1 + 2048];
        #pragma unroll
        for (int ct = 0; ct < 4; ++ct) {
            bf16x8 bh = *(const bf16x8*)&smW[N2 + (kt * 4 + ct) * 512 + lane * 8];
            bf16x8 bl = *(const bf16x8*)&smW[N2 + 4096 + (kt * 4 + ct) * 512 + lane * 8];
            MFMA16(ah0, bh, oacc[0][ct]);
            MFMA16(ah1, bh, oacc[1][ct]);
            MFMA16(al0, bh, oacc[0][ct]);
            MFMA16(al1, bh, oacc[1][ct]);
            MFMA16(ah0, bl, oacc[0][ct]);
            MFMA16(ah1, bl, oacc[1][ct]);
        }
    }

    #pragma unroll
    for (int rt = 0; rt < 2; ++rt)
        #pragma unroll
        for (int ct = 0; ct < 4; ++ct)
            #pragma unroll
            for (int i = 0; i < 4; ++i) {
                const int rl = wid * 32 + rt * 16 + 4 * q + i;
                const int col = ct * 16 + n;
                const float v = oacc[rt][ct][i];
                atomicAdd(&g_acc[(size_t)srow[rl] * 64 + col], v);
                if constexpr (!FRAG_OUT)
                    fout[(size_t)(e0 + rl) * 64 + col] = v;   // ex4: pre-relu f32
            }
    if constexpr (FRAG_OUT)
        frag_store_o(hreg, wid, lane, oacc, Ffrag, blockIdx.x);
}

template<int NSF, bool HASQ2, bool FRAG_OUT>
__global__ void __launch_bounds__(256, 3) edge_lite(
        const u16* f0, const u16* f1, const void* b1, const void* b2,
        u16* Ffrag, float* fout, int wpAoff, int wp2off) {
    __shared__ __align__(16) u16 smW[24576];
    __shared__ int srow[128], scol[128];
    __shared__ float b1s[64], b2s[64];
    if (g_mode == 0)
        edge_lite_body<u16, NSF, HASQ2, FRAG_OUT>(smW, srow, scol, b1s, b2s,
            f0, f1, (const u16*)b1, (const u16*)b2, Ffrag, fout, wpAoff, wp2off);
    else
        edge_lite_body<float, NSF, HASQ2, FRAG_OUT>(smW, srow, scol, b1s, b2s,
            f0, f1, (const float*)b1, (const float*)b2, Ffrag, fout, wpAoff, wp2off);
}

// --- tail: blocks [0,2500) final_node ; [2500,2750) edge_head ---------------
template<typename T>
__device__ void final_node_body(const T* w, const T* b, T* out, int bid) {
    const int t = threadIdx.x;
    const int lane = t & 63;
    const int n = bid * 4 + (t >> 6);
    float inv = 1.0f / fmaxf(g_deg[n], 1.0f);
    float x4 = fmaxf(g_acc[(size_t)n * 64 + lane] * inv, 0.0f);
    float r[4];
    #pragma unroll
    for (int j = 0; j < 4; ++j) {
        float v = x4 * ldf(w + lane * 4 + j);
        #pragma unroll
        for (int off = 32; off >= 1; off >>= 1) v += __shfl_xor(v, off);
        r[j] = v + ldf(b + j);
    }
    float nrm = sqrtf(r[0]*r[0] + r[1]*r[1] + r[2]*r[2] + r[3]*r[3]);
    float dn = fmaxf(nrm, 1e-12f);
    if (lane < 4) stf(out + n * 4 + lane, r[lane] / dn);
}

template<typename T>
__device__ void edge_head_body(const float* ex4, const T* w1, const T* b1,
                               const T* w2, const T* b2, T* out, int bid) {
    __shared__ float lw1[2048];
    __shared__ float lw2[32];
    const int t = threadIdx.x;
    for (int i = t; i < 2048; i += 256) lw1[i] = ldf(w1 + i);
    if (t < 32) lw2[t] = ldf(w2 + t);
    __syncthreads();
    const int e = bid * 256 + t;                  // exact: 250*256 = 64000
    float a[32];
    #pragma unroll
    for (int j = 0; j < 32; ++j) a[j] = ldf(b1 + j);
    const float* p0 = ex4 + (size_t)e * 64;
    const float* p1 = ex4 + (size_t)(e + E_HALF) * 64;
    for (int c = 0; c < 64; ++c) {
        float h = p0[c] + p1[c];
        #pragma unroll
        for (int j = 0; j < 32; ++j) a[j] += h * lw1[c * 32 + j];
    }
    float s = ldf(b2);
    #pragma unroll
    for (int j = 0; j < 32; ++j) s += fmaxf(a[j], 0.f) * lw2[j];
    stf(out + e, s);
}

__global__ void __launch_bounds__(256) tail_k(
        const void* lw, const void* lb, const float* ex4,
        const void* ew1, const void* eb1, const void* ew2, const void* eb2,
        void* out) {
    const int b = blockIdx.x;
    if (b < 2500) {
        if (g_mode == 0) final_node_body<u16>((const u16*)lw, (const u16*)lb, (u16*)out, b);
        else             final_node_body<float>((const float*)lw, (const float*)lb, (float*)out, b);
    } else {
        if (g_mode == 0)
            edge_head_body<u16>(ex4, (const u16*)ew1, (const u16*)eb1,
                (const u16*)ew2, (const u16*)eb2, (u16*)out + 40000, b - 2500);
        else
            edge_head_body<float>(ex4, (const float*)ew1, (const float*)eb1,
                (const float*)ew2, (const float*)eb2, (float*)out + 40000, b - 2500);
    }
}

// --- layout tripwire: fill out with ~996.5 pattern --------------------------
__global__ void sentinel_fill(unsigned int* out, int n_words) {
    int i = blockIdx.x * 256 + threadIdx.x;
    if (i < n_words) out[i] = 0x44794479u;
}

static void* sym_addr(const void* symbol) {
    void* p = nullptr;
    (void)hipGetSymbolAddress(&p, symbol);
    return p;
}

extern "C" void kernel_launch(void* const* d_in, const int* in_sizes, int n_in,
                              void* d_out, int out_size, void* d_ws, size_t ws_size,
                              hipStream_t stream) {
    (void)d_ws; (void)ws_size;
    bool ok = (n_in == 27) && (out_size == 104000)
           && (in_sizes[0] == 2560000) && (in_sizes[2] == 256000)
           && (in_sizes[3] == 81920000) && (in_sizes[5] == 74496)
           && (in_sizes[21] == 256) && (in_sizes[25] == 32);
    if (!ok) {   // wrong layout assumption -> recognizable absmax ~996
        sentinel_fill<<<204, 256, 0, stream>>>((unsigned int*)d_out, 52000);
        return;
    }
    const void* x_org     = d_in[0];
    const void* x_rot     = d_in[1];
    const int*  eidx      = (const int*)d_in[2];
    const void* edge_attr = d_in[3];
    const void* edge_rot  = d_in[4];

    float* P   = (float*)sym_addr(HIP_SYMBOL(g_P));
    float* x1  = (float*)sym_addr(HIP_SYMBOL(g_x1));
    float* x2  = (float*)sym_addr(HIP_SYMBOL(g_x2));
    float* x3  = (float*)sym_addr(HIP_SYMBOL(g_x3));
    u16*   fA  = (u16*)sym_addr(HIP_SYMBOL(g_fragA));
    u16*   fB  = (u16*)sym_addr(HIP_SYMBOL(g_fragB));
    float* ex4 = (float*)sym_addr(HIP_SYMBOL(g_ex4));

    // 1. zero acc/deg + dtype/idx detect
    prologue_a<<<2500, 256, 0, stream>>>(x_org, eidx);
    // 2. all weight packs (752 blocks) + idx convert + degree (500 blocks)
    prep_k<<<1252, 256, 0, stream>>>(d_in[5], d_in[7], d_in[9], d_in[11],
                                     d_in[13], d_in[15], d_in[17], d_in[19], eidx);

    // conv1 (+fused Q2 for conv2)
    node_mfma_in<<<157, 256, 0, stream>>>(x_org, x_rot, d_in[5], P);
    edge_c1<<<NBLK, 256, 0, stream>>>(edge_attr, edge_rot, d_in[5], d_in[6], d_in[8]);

    // conv2: node GEMM fused with x1 = acc/deg (no relu), zero acc
    node_mfma_acc<0, false><<<157, 256, 0, stream>>>(nullptr, x1, P, 4 * 8192);
    edge_lite<1, true, true><<<NBLK, 256, 0, stream>>>(
        fA, nullptr, d_in[10], d_in[12], fB, nullptr, 0, 4096);           // ex2

    // conv3: x2 = relu(acc/deg); A = [x2|x1]
    node_mfma_acc<1, true><<<157, 256, 0, stream>>>(x1, x2, P, 5 * 8192);
    edge_lite<2, false, true><<<NBLK, 256, 0, stream>>>(
        fB, fA, d_in[14], d_in[16], fA, nullptr, 4096, 8192);             // ex3 over ex1
    // conv4: x3 = relu(acc/deg); A = [x3|x2]
    node_mfma_acc<1, true><<<157, 256, 0, stream>>>(x2, x3, P, 7 * 8192);
    edge_lite<2, false, false><<<NBLK, 256, 0, stream>>>(
        fA, fB, d_in[18], d_in[20], nullptr, ex4, 12288, 12288);          // ex4

    // x4 -> lin1 -> normalize (reads g_acc directly) + edge head
    tail_k<<<2750, 256, 0, stream>>>(d_in[21], d_in[22], ex4,
                                     d_in[23], d_in[24], d_in[25], d_in[26], d_out);
}

// Round 10
// 790.233 us; speedup vs baseline: 1.0431x; 1.0431x over previous
//
#include <hip/hip_runtime.h>
#include <stdint.h>

// ---------------------------------------------------------------------------
// Net_52948356825721: 4x edge-conv GNN.
// R4: edge MLPs -> MFMA split-bf16 (hi/lo, 3 products): 1795 -> 969 us.
// R5: node GEMMs -> MFMA; staging bank swizzle: 969 -> 922 us.
// R6: Q2 fusion (conv2 K 704->64) + ex frag-order global scratch: 943 us.
// R7: LDS-free A-path + reg ping-pong: 896 us.
// R8: edge_c1 W dbuf LDS via global_load_lds + counted vmcnt: 843 us.
// R9: launch-graph consolidation 24 -> 11 dispatches: 820 us.
// R10: edge_lite 3 blocks/CU + Q2 lane-major layout: 821 us (neutral).
// R11: half-step W staging: 824 us (neutral; edge_c1 200us stall-bound).
// R12: macro-expanded 20-body K-loop (named A bufs lead-2, W ring-3 lead-1,
//      one barrier/iter, counted vmcnt, setprio) -- FAILED absmax 0.033:
//      A-ring consume/fill mismatch at h>=10 (pre-registered signature).
// R13: mechanical fix: strict period-4 A-ring chain. Invariant:
//      consume(H) = a[H%4], fill(H) -> a[(H+2)%4]  (= data for h=H+2).
//      vmcnt ladder unchanged (steady 12 drains A(h),W(h); tails 8/0).
//      No other changes (clean attribution of the R12 schedule).
// k-slot bijection k = 4q + (r&3) + 16(r>>2) shared by A-frags and W packs.
// C/D: col = lane&15, row = 4*(lane>>4)+reg.
// ---------------------------------------------------------------------------

#define N_NODES 10000
#define N_EDGES 128000
#define E_HALF  64000
#define NBLK    1000          // 128-edge blocks

typedef unsigned short u16;

using bf16x8 = __attribute__((ext_vector_type(8))) short;
using f32x4  = __attribute__((ext_vector_type(4))) float;

#define MFMA16(A, B, C) C = __builtin_amdgcn_mfma_f32_16x16x32_bf16(A, B, C, 0, 0, 0)

__device__ __align__(256) float g_acc[N_NODES * 64];
__device__ __align__(256) float g_deg[N_NODES];
__device__ __align__(256) float g_P[N_NODES * 128];
__device__ __align__(256) float g_x1[N_NODES * 64];
__device__ __align__(256) float g_x2[N_NODES * 64];
__device__ __align__(256) float g_x3[N_NODES * 64];
__device__ __align__(256) u16  g_fragA[(size_t)NBLK * 16384];  // ex1, later ex3
__device__ __align__(256) u16  g_fragB[(size_t)NBLK * 16384];  // ex2
__device__ __align__(256) float g_Q2 [(size_t)NBLK * 8192];    // lane-major frag layout
__device__ __align__(256) float g_ex4[(size_t)N_EDGES * 64];   // conv4 out (f32)
__device__ __align__(256) u16  g_wpA_hi[5 * 4096];   // edge W1 packs: c2@0, c3@4096, c4@12288
__device__ __align__(256) u16  g_wpA_lo[5 * 4096];
__device__ __align__(256) u16  g_wp2_hi[4 * 4096];   // edge W2 packs: c1..c4
__device__ __align__(256) u16  g_wp2_lo[4 * 4096];
__device__ __align__(256) u16  g_wnp_hi[9 * 8192];   // node W packs: c1@0(4), c2@4, c3@5, c4@7
__device__ __align__(256) u16  g_wnp_lo[9 * 8192];
__device__ __align__(256) u16  g_wpC_hi[10 * 8192];  // conv1 combined pack (8-ct)
__device__ __align__(256) u16  g_wpC_lo[10 * 8192];
__device__ __align__(256) int g_row[N_EDGES];
__device__ __align__(256) int g_col[N_EDGES];
__device__ int g_mode;   // 0 = bf16 I/O, 1 = f32 I/O
__device__ int g_is64;   // edge_index is int64

__device__ __forceinline__ float b2f(u16 u) {
    return __uint_as_float(((unsigned int)u) << 16);
}
__device__ __forceinline__ u16 f2b(float f) {
    unsigned int u = __float_as_uint(f);
    u += 0x7FFFu + ((u >> 16) & 1u);   // RNE
    return (u16)(u >> 16);
}
__device__ __forceinline__ float ldf(const u16* p)   { return b2f(*p); }
__device__ __forceinline__ float ldf(const float* p) { return *p; }
__device__ __forceinline__ void  stf(u16* p, float v)   { *p = f2b(v); }
__device__ __forceinline__ void  stf(float* p, float v) { *p = v; }

__device__ __forceinline__ float4 load4(const float* p) { return *(const float4*)p; }
__device__ __forceinline__ float4 load4(const u16* p) {
    ushort4 v = *(const ushort4*)p;
    return make_float4(b2f(v.x), b2f(v.y), b2f(v.z), b2f(v.w));
}

// async global->LDS, 16B per lane: LDS dest = base + lane*16 (HW), src per-lane
__device__ __forceinline__ void gl_lds16(const void* g, void* l) {
    __builtin_amdgcn_global_load_lds(
        (const __attribute__((address_space(1))) void*)g,
        (__attribute__((address_space(3))) void*)l, 16, 0, 0);
}

// split 4 f32 into packed bf16 hi (truncation) + lo (RNE of exact residual)
__device__ __forceinline__ void split_pack(float4 v, uint2& hi, uint2& lo) {
    unsigned int ux = __float_as_uint(v.x), uy = __float_as_uint(v.y);
    unsigned int uz = __float_as_uint(v.z), uw = __float_as_uint(v.w);
    unsigned int hx = ux & 0xFFFF0000u, hy = uy & 0xFFFF0000u;
    unsigned int hz = uz & 0xFFFF0000u, hw = uw & 0xFFFF0000u;
    hi.x = (hx >> 16) | hy;
    hi.y = (hz >> 16) | hw;
    u16 lx = f2b(v.x - __uint_as_float(hx));
    u16 ly = f2b(v.y - __uint_as_float(hy));
    u16 lz = f2b(v.z - __uint_as_float(hz));
    u16 lw = f2b(v.w - __uint_as_float(hw));
    lo.x = (unsigned int)lx | ((unsigned int)ly << 16);
    lo.y = (unsigned int)lz | ((unsigned int)lw << 16);
}

// build A-fragment (hi/lo planes) from the two float4 halves:
// v0 -> frag words 0,1 (k = 4q+{0..3}); v1 -> words 2,3 (k = 4q+16+{0..3})
__device__ __forceinline__ void mk_frag(float4 v0, float4 v1,
                                        bf16x8& fh, bf16x8& fl) {
    uint2 h0, l0, h1, l1;
    split_pack(v0, h0, l0);
    split_pack(v1, h1, l1);
    union { unsigned int w[4]; bf16x8 v; } H, L;
    H.w[0] = h0.x; H.w[1] = h0.y; H.w[2] = h1.x; H.w[3] = h1.y;
    L.w[0] = l0.x; L.w[1] = l0.y; L.w[2] = l1.x; L.w[3] = l1.y;
    fh = H.v; fl = L.v;
}

// --- prologue A: zero acc/deg + dtype/idx-width detection -------------------
__global__ void prologue_a(const void* x_org_v, const int* __restrict__ eidx) {
    const int i = blockIdx.x * 256 + threadIdx.x;   // exact 2500*256 = 640000
    g_acc[i] = 0.f;
    if (i < N_NODES) g_deg[i] = 0.f;
    if (blockIdx.x == 0 && threadIdx.x < 64) {
        const u16* w = (const u16*)x_org_v;
        const int t = threadIdx.x;
        int ok = 0;
        for (int j = t; j < 128; j += 64) {
            u16 v = w[j];
            int ex = (v >> 7) & 0xFF;
            ok += ((ex >= 0x68 && ex <= 0x88) || ((v & 0x7FFFu) == 0)) ? 1 : 0;
        }
        #pragma unroll
        for (int off = 32; off >= 1; off >>= 1) ok += __shfl_xor(ok, off);
        bool allz = true;
        for (int j = t; j < 2048; j += 64) allz = allz && (eidx[2 * j + 1] == 0);
        unsigned long long m = __ballot(allz);
        if (t == 0) {
            g_mode = (ok >= 110) ? 0 : 1;
            g_is64 = (m == ~0ull) ? 1 : 0;
        }
    }
}

// --- weight pre-pack primitives ---------------------------------------------
__device__ __forceinline__ void pack_pair(u16* dh, u16* dl, float v) {
    const u16 hh = f2b(v);
    *dh = hh; *dl = f2b(v - b2f(hh));
}
// node pack (8-ct): rem in [0, ns*8192)
template<typename TW>
__device__ void pack_wnp(const TW* w, int hioff, int rem, u16* dh, u16* dl) {
    const int s = rem >> 13, kt = (rem >> 12) & 1, ct = (rem >> 9) & 7,
              l = (rem >> 3) & 63, r = rem & 7;
    const int k = s * 64 + kt * 32 + 4 * (l >> 4) + (r & 3) + 16 * (r >> 2);
    const int col = ct * 16 + (l & 15);
    const int row = (col < 64) ? k : (hioff + k);
    pack_pair(dh + rem, dl + rem, ldf(w + (size_t)row * 64 + (col & 63)));
}
// 4-ct pack with row offset we (wp2 = we 0, 1 step)
template<typename TW>
__device__ void pack_wpa(const TW* w, int we, int rem, u16* dh, u16* dl) {
    const int s = rem >> 12, kt = (rem >> 11) & 1, ct = (rem >> 9) & 3,
              l = (rem >> 3) & 63, r = rem & 7;
    const int k = s * 64 + kt * 32 + 4 * (l >> 4) + (r & 3) + 16 * (r >> 2);
    pack_pair(dh + rem, dl + rem,
              ldf(w + (size_t)(we + k) * 64 + ct * 16 + (l & 15)));
}
// conv1 combined 8-ct: cols 0-63 c1_w1[520+k], 64-127 c2_w1[128+k]
template<typename TW>
__device__ void pack_wpc(const TW* w1, const TW* w2w, int rem) {
    const int s = rem >> 13, kt = (rem >> 12) & 1, ct = (rem >> 9) & 7,
              l = (rem >> 3) & 63, r = rem & 7;
    const int k = s * 64 + kt * 32 + 4 * (l >> 4) + (r & 3) + 16 * (r >> 2);
    const int col = ct * 16 + (l & 15);
    float v = (col < 64) ? ldf(w1 + (size_t)(520 + k) * 64 + col)
                         : ldf(w2w + (size_t)(128 + k) * 64 + (col - 64));
    pack_pair(g_wpC_hi + rem, g_wpC_lo + rem, v);
}

template<typename TW>
__device__ void pack_all_body(const TW* c1w1, const TW* c1w2, const TW* c2w1,
        const TW* c2w2, const TW* c3w1, const TW* c3w2, const TW* c4w1,
        const TW* c4w2) {
    const int idx = blockIdx.x * 256 + threadIdx.x;
    if (idx < 81920)        pack_wpc<TW>(c1w1, c2w1, idx);
    else if (idx < 114688)  pack_wnp<TW>(c1w1, 260, idx - 81920,  g_wnp_hi,            g_wnp_lo);
    else if (idx < 122880)  pack_wnp<TW>(c2w1, 64,  idx - 114688, g_wnp_hi + 4 * 8192, g_wnp_lo + 4 * 8192);
    else if (idx < 139264)  pack_wnp<TW>(c3w1, 128, idx - 122880, g_wnp_hi + 5 * 8192, g_wnp_lo + 5 * 8192);
    else if (idx < 155648)  pack_wnp<TW>(c4w1, 128, idx - 139264, g_wnp_hi + 7 * 8192, g_wnp_lo + 7 * 8192);
    else if (idx < 159744)  pack_wpa<TW>(c2w1, 768, idx - 155648, g_wpA_hi,            g_wpA_lo);
    else if (idx < 167936)  pack_wpa<TW>(c3w1, 256, idx - 159744, g_wpA_hi + 4096,     g_wpA_lo + 4096);
    else if (idx < 176128)  pack_wpa<TW>(c4w1, 256, idx - 167936, g_wpA_hi + 12288,    g_wpA_lo + 12288);
    else if (idx < 180224)  pack_wpa<TW>(c1w2, 0,   idx - 176128, g_wp2_hi,            g_wp2_lo);
    else if (idx < 184320)  pack_wpa<TW>(c2w2, 0,   idx - 180224, g_wp2_hi + 4096,     g_wp2_lo + 4096);
    else if (idx < 188416)  pack_wpa<TW>(c3w2, 0,   idx - 184320, g_wp2_hi + 8192,     g_wp2_lo + 8192);
    else if (idx < 192512)  pack_wpa<TW>(c4w2, 0,   idx - 188416, g_wp2_hi + 12288,    g_wp2_lo + 12288);
}

// --- prep: blocks [0,752) pack all weights; [752,1252) idx convert + degree -
__global__ void prep_k(const void* c1w1, const void* c1w2, const void* c2w1,
        const void* c2w2, const void* c3w1, const void* c3w2, const void* c4w1,
        const void* c4w2, const int* __restrict__ eidx) {
    if ((int)blockIdx.x < 752) {
        if (g_mode == 0)
            pack_all_body<u16>((const u16*)c1w1, (const u16*)c1w2, (const u16*)c2w1,
                (const u16*)c2w2, (const u16*)c3w1, (const u16*)c3w2,
                (const u16*)c4w1, (const u16*)c4w2);
        else
            pack_all_body<float>((const float*)c1w1, (const float*)c1w2,
                (const float*)c2w1, (const float*)c2w2, (const float*)c3w1,
                (const float*)c3w2, (const float*)c4w1, (const float*)c4w2);
    } else {
        const int e = ((int)blockIdx.x - 752) * 256 + threadIdx.x;  // 500*256
        int row, col;
        if (g_is64) { row = eidx[2 * e]; col = eidx[2 * (e + N_EDGES)]; }
        else        { row = eidx[e];     col = eidx[e + N_EDGES]; }
        g_row[e] = row; g_col[e] = col;
        atomicAdd(&g_deg[row], 1.0f);
    }
}

// --- conv1 node GEMM: P = [x_org|x_rot] @ [W_r|W_c] (K=260, rot VALU tail) --
template<typename TA>
__device__ void node_mfma_in_body(float* smrot, float* smwt,
        const TA* A1, const TA* rotsrc, const TA* w1, float* P) {
    const int t = threadIdx.x;
    const int lane = t & 63, wid = t >> 6;
    const int q = lane >> 4, n = lane & 15;
    const int r0b = blockIdx.x * 64;

    if (t < 64) {
        const int rr = min(r0b + t, N_NODES - 1);
        float4 v = load4(rotsrc + (size_t)rr * 4);
        smrot[t * 4 + 0] = v.x; smrot[t * 4 + 1] = v.y;
        smrot[t * 4 + 2] = v.z; smrot[t * 4 + 3] = v.w;
    }
    for (int i = t; i < 512; i += 256) {
        const int j = i >> 7, c = i & 127;
        const int row = (c < 64) ? (256 + j) : (516 + j);
        smwt[i] = ldf(w1 + (size_t)row * 64 + (c & 63));
    }
    __syncthreads();

    const int arow = min(r0b + wid * 16 + n, N_NODES - 1);

    f32x4 acc[8];
    #pragma unroll
    for (int ct = 0; ct < 8; ++ct) acc[ct] = (f32x4){0.f, 0.f, 0.f, 0.f};

    #pragma unroll
    for (int s = 0; s < 4; ++s) {
        #pragma unroll
        for (int kt = 0; kt < 2; ++kt) {
            const TA* p = A1 + (size_t)arow * 256 + s * 64 + kt * 32 + q * 4;
            float4 v0 = load4(p), v1 = load4(p + 16);
            bf16x8 ah, al;
            mk_frag(v0, v1, ah, al);
            const u16* wph = g_wnp_hi + s * 8192;
            const u16* wpl = g_wnp_lo + s * 8192;
            #pragma unroll
            for (int ct = 0; ct < 8; ++ct) {
                bf16x8 bh = *(const bf16x8*)&wph[(kt * 8 + ct) * 512 + lane * 8];
                bf16x8 bl = *(const bf16x8*)&wpl[(kt * 8 + ct) * 512 + lane * 8];
                MFMA16(ah, bh, acc[ct]);
                MFMA16(al, bh, acc[ct]);
                MFMA16(ah, bl, acc[ct]);
            }
        }
    }

    #pragma unroll
    for (int ct = 0; ct < 8; ++ct) {
        #pragma unroll
        for (int i = 0; i < 4; ++i) {
            const int rl = wid * 16 + 4 * q + i;
            const int row = r0b + rl;
            const int col = ct * 16 + n;
            float v = acc[ct][i]
                    + smrot[rl * 4 + 0] * smwt[0 * 128 + col]
                    + smrot[rl * 4 + 1] * smwt[1 * 128 + col]
                    + smrot[rl * 4 + 2] * smwt[2 * 128 + col]
                    + smrot[rl * 4 + 3] * smwt[3 * 128 + col];
            if (row < N_NODES) P[(size_t)row * 128 + col] = v;
        }
    }
}

__global__ void __launch_bounds__(256) node_mfma_in(
        const void* A1, const void* rotsrc, const void* w1, float* __restrict__ P) {
    __shared__ float smrot[256], smwt[512];
    if (g_mode == 0)
        node_mfma_in_body<u16>(smrot, smwt, (const u16*)A1, (const u16*)rotsrc,
                               (const u16*)w1, P);
    else
        node_mfma_in_body<float>(smrot, smwt, (const float*)A1, (const float*)rotsrc,
                               (const float*)w1, P);
}

// --- convs 2-4 node GEMM with FUSED finalize: A1 = [relu](acc/deg) ----------
template<int NS2, bool RELU>
__global__ void __launch_bounds__(256) node_mfma_acc(
        const float* A2, float* __restrict__ xout, float* __restrict__ P,
        int wnpoff) {
    const int t = threadIdx.x;
    const int lane = t & 63, wid = t >> 6;
    const int q = lane >> 4, n = lane & 15;
    const int r0b = blockIdx.x * 64;
    const int rown = r0b + wid * 16 + n;
    const int arow = min(rown, N_NODES - 1);
    const bool own = rown < N_NODES;
    const float inv = 1.0f / fmaxf(g_deg[arow], 1.0f);

    f32x4 acc[8];
    #pragma unroll
    for (int ct = 0; ct < 8; ++ct) acc[ct] = (f32x4){0.f, 0.f, 0.f, 0.f};

    // s = 0: A from g_acc
    #pragma unroll
    for (int kt = 0; kt < 2; ++kt) {
        float* p = g_acc + (size_t)arow * 64 + kt * 32 + q * 4;
        float4 v0 = load4(p), v1 = load4(p + 16);
        v0.x *= inv; v0.y *= inv; v0.z *= inv; v0.w *= inv;
        v1.x *= inv; v1.y *= inv; v1.z *= inv; v1.w *= inv;
        if (RELU) {
            v0.x = fmaxf(v0.x, 0.f); v0.y = fmaxf(v0.y, 0.f);
            v0.z = fmaxf(v0.z, 0.f); v0.w = fmaxf(v0.w, 0.f);
            v1.x = fmaxf(v1.x, 0.f); v1.y = fmaxf(v1.y, 0.f);
            v1.z = fmaxf(v1.z, 0.f); v1.w = fmaxf(v1.w, 0.f);
        }
        if (own) {   // clamped dup lanes must not write (read-after-zero race)
            *(float4*)(xout + (size_t)arow * 64 + kt * 32 + q * 4) = v0;
            *(float4*)(xout + (size_t)arow * 64 + kt * 32 + q * 4 + 16) = v1;
            *(float4*)p = make_float4(0.f, 0.f, 0.f, 0.f);
            *(float4*)(p + 16) = make_float4(0.f, 0.f, 0.f, 0.f);
        }
        bf16x8 ah, al;
        mk_frag(v0, v1, ah, al);
        const u16* wph = g_wnp_hi + wnpoff;
        const u16* wpl = g_wnp_lo + wnpoff;
        #pragma unroll
        for (int ct = 0; ct < 8; ++ct) {
            bf16x8 bh = *(const bf16x8*)&wph[(kt * 8 + ct) * 512 + lane * 8];
            bf16x8 bl = *(const bf16x8*)&wpl[(kt * 8 + ct) * 512 + lane * 8];
            MFMA16(ah, bh, acc[ct]);
            MFMA16(al, bh, acc[ct]);
            MFMA16(ah, bl, acc[ct]);
        }
    }
    if constexpr (NS2 > 0) {   // s = 1: A from previous conv's x (materialized)
        #pragma unroll
        for (int kt = 0; kt < 2; ++kt) {
            const float* p = A2 + (size_t)arow * 64 + kt * 32 + q * 4;
            float4 v0 = load4(p), v1 = load4(p + 16);
            bf16x8 ah, al;
            mk_frag(v0, v1, ah, al);
            const u16* wph = g_wnp_hi + wnpoff + 8192;
            const u16* wpl = g_wnp_lo + wnpoff + 8192;
            #pragma unroll
            for (int ct = 0; ct < 8; ++ct) {
                bf16x8 bh = *(const bf16x8*)&wph[(kt * 8 + ct) * 512 + lane * 8];
                bf16x8 bl = *(const bf16x8*)&wpl[(kt * 8 + ct) * 512 + lane * 8];
                MFMA16(ah, bh, acc[ct]);
                MFMA16(al, bh, acc[ct]);
                MFMA16(ah, bl, acc[ct]);
            }
        }
    }

    #pragma unroll
    for (int ct = 0; ct < 8; ++ct) {
        #pragma unroll
        for (int i = 0; i < 4; ++i) {
            const int rl = wid * 16 + 4 * q + i;
            const int row = r0b + rl;
            if (row < N_NODES) P[(size_t)row * 128 + ct * 16 + n] = acc[ct][i];
        }
    }
}

// --- o-frag repack via wave LDS region + coalesced global store -------------
__device__ __forceinline__ void frag_store_o(u16* hreg, int wid, int lane,
        const f32x4 (&oacc)[2][4], u16* Fdst, int blkid) {
    const int q = lane >> 4, n = lane & 15;
    #pragma unroll
    for (int rt = 0; rt < 2; ++rt)
        #pragma unroll
        for (int ct = 0; ct < 4; ++ct)
            #pragma unroll
            for (int i = 0; i < 4; ++i) {
                float v = fmaxf(oacc[rt][ct][i], 0.f);   // relu'd edge feature
                unsigned int hb = __float_as_uint(v) & 0xFFFF0000u;
                const u16 hh = (u16)(hb >> 16);
                const u16 hl = f2b(v - __uint_as_float(hb));
                const int off = wid * 4096
                              + (((ct >> 1) * 2 + rt) * 64 + (n >> 2) * 16 + 4 * q + i) * 8
                              + (ct & 1) * 4 + (n & 3);
                hreg[off]        = hh;
                hreg[off + 2048] = hl;
            }
    #pragma unroll
    for (int kt = 0; kt < 2; ++kt)
        #pragma unroll
        for (int rtl = 0; rtl < 2; ++rtl) {
            const int src = wid * 4096 + ((kt * 2 + rtl) * 64 + lane) * 8;
            bf16x8 h8 = *(const bf16x8*)&hreg[src];
            bf16x8 l8 = *(const bf16x8*)&hreg[src + 2048];
            const size_t gb = (size_t)blkid * 16384
                            + (size_t)(kt * 8 + wid * 2 + rtl) * 512 + lane * 8;
            *(bf16x8*)&Fdst[gb]        = h8;
            *(bf16x8*)&Fdst[gb + 8192] = l8;
        }
}

// --- conv1 fused: h1 path + Q2 = edge_attr @ c2_w1[128:768] -----------------
// R12/R13 schedule: macro-expanded 20 half-step bodies, all-literal indices.
// smW bytes: [0,16K) W buf0 | [16K,32K) buf1 | [32K,48K) buf2 | [48K,64K) wp2.
// W ring-3, lead-1, ONE barrier/iter; A: 4 named reg buffers, lead-2,
// STRICT period-4: consume(H)=a[H%4], fill(H)->a[(H+2)%4].
// Waits: prologue vmcnt(12) -> [W0,A0,A1]; steady vmcnt(12) drains A(h),W(h);
// h=18 vmcnt(8); h=19 vmcnt(0). hreg overlays [0,32K) after a barrier.
template<typename TA, typename TW>
__device__ void edge_c1_body(u16* smW, int* srow, int* scol,
        float* b1s, float* b2s, float* rot, float* wtl,
        const TA* efa, const TA* rotsrc,
        const TW* w1, const TW* b1v, const TW* b2v) {
    const int t = threadIdx.x;
    const int lane = t & 63, wid = t >> 6;
    const int q = lane >> 4, n = lane & 15;
    const int e0 = blockIdx.x * 128;

    // stage wp2 once into bytes [49152, 65536)  (oldest in vmcnt queue)
    #pragma unroll
    for (int i = 0; i < 4; ++i) {
        const int L = wid * 4096 + i * 1024;
        const char* src = (L < 8192) ? (const char*)g_wp2_hi + L
                                     : (const char*)g_wp2_lo + (L - 8192);
        gl_lds16(src + lane * 16, (char*)smW + 49152 + L);
    }

    if (t < 128) srow[t] = g_row[e0 + t];
    else         scol[t - 128] = g_col[e0 + t - 128];
    if (t >= 128 && t < 192) b1s[t - 128] = ldf(b1v + (t - 128));
    if (t >= 192)            b2s[t - 192] = ldf(b2v + (t - 192));
    if (t < 128) {
        float4 r4 = load4(rotsrc + (size_t)(e0 + t) * 4);
        rot[t * 4 + 0] = r4.x; rot[t * 4 + 1] = r4.y;
        rot[t * 4 + 2] = r4.z; rot[t * 4 + 3] = r4.w;
    }
    wtl[t] = ldf(w1 + (size_t)(1160 + (t >> 6)) * 64 + (t & 63));

    const TA* arow0 = efa + (size_t)(e0 + wid * 32 + n) * 640;
    const TA* arow1 = efa + (size_t)(e0 + wid * 32 + 16 + n) * 640;

    f32x4 acc[2][8];
    #pragma unroll
    for (int a_ = 0; a_ < 2; ++a_)
        #pragma unroll
        for (int b_ = 0; b_ < 8; ++b_)
            acc[a_][b_] = (f32x4){0.f, 0.f, 0.f, 0.f};

    // stage 16KB half-step h -> W ring buf (byte base). 2KB hi + 2KB lo /wave.
    auto stageW = [&](int h, int bufbyte) {
        const char* sh = (const char*)g_wpC_hi + (size_t)h * 8192;
        const char* sl = (const char*)g_wpC_lo + (size_t)h * 8192;
        char* d = (char*)smW + bufbyte;
        #pragma unroll
        for (int i = 0; i < 2; ++i) {
            const int off = wid * 2048 + i * 1024;
            gl_lds16(sh + off + lane * 16, d + off);
            gl_lds16(sl + off + lane * 16, d + 8192 + off);
        }
    };
    auto issueA = [&](float4 (&buf)[2][2], int h) {   // 4 load4 (lead-2)
        const int cb = (h >> 1) * 64 + (h & 1) * 32 + q * 4;
        buf[0][0] = load4(arow0 + cb);
        buf[0][1] = load4(arow0 + cb + 16);
        buf[1][0] = load4(arow1 + cb);
        buf[1][1] = load4(arow1 + cb + 16);
    };
    auto step = [&](float4 (&buf)[2][2], int wb_u16) { // 48 MFMA
        bf16x8 ah0, al0, ah1, al1;
        mk_frag(buf[0][0], buf[0][1], ah0, al0);
        mk_frag(buf[1][0], buf[1][1], ah1, al1);
        #pragma unroll
        for (int ct = 0; ct < 8; ++ct) {
            bf16x8 bh = *(const bf16x8*)&smW[wb_u16 + ct * 512 + lane * 8];
            bf16x8 bl = *(const bf16x8*)&smW[wb_u16 + 4096 + ct * 512 + lane * 8];
            MFMA16(ah0, bh, acc[0][ct]);
            MFMA16(ah1, bh, acc[1][ct]);
            MFMA16(al0, bh, acc[0][ct]);
            MFMA16(al1, bh, acc[1][ct]);
            MFMA16(ah0, bl, acc[0][ct]);
            MFMA16(ah1, bl, acc[1][ct]);
        }
    };

    float4 a0[2][2], a1[2][2], a2[2][2], a3[2][2];

    // prologue: wp2 + scalars already issued; add W0, A0, A1; drain everything
    // older than [W0, A0, A1] (12 outstanding), then sync.
    stageW(0, 0);
    issueA(a0, 0);
    issueA(a1, 1);
    __builtin_amdgcn_sched_barrier(0);
    asm volatile("s_waitcnt vmcnt(12) lgkmcnt(0)");
    __builtin_amdgcn_sched_barrier(0);
    __builtin_amdgcn_s_barrier();

// one body: stage W(h+1) ring-3, issue A(h+2) -> a[(h+2)%4], counted wait,
// ONE barrier, setprio'd MFMA cluster. All indices literal.
#define C1B(H, AC, AN, VM)                                                    \
    do {                                                                      \
        if constexpr ((H) < 19) stageW((H) + 1, (((H) + 1) % 3) * 16384);     \
        if constexpr ((H) < 18) issueA(AN, (H) + 2);                          \
        __builtin_amdgcn_sched_barrier(0);                                    \
        asm volatile("s_waitcnt vmcnt(" VM ")");                              \
        __builtin_amdgcn_sched_barrier(0);                                    \
        __builtin_amdgcn_s_barrier();                                         \
        __builtin_amdgcn_s_setprio(1);                                        \
        step(AC, ((H) % 3) * 8192);                                           \
        __builtin_amdgcn_s_setprio(0);                                        \
    } while (0)

    // STRICT period-4: AC = a[H%4], AN = a[(H+2)%4]
    C1B(0,  a0, a2, "12"); C1B(1,  a1, a3, "12");
    C1B(2,  a2, a0, "12"); C1B(3,  a3, a1, "12");
    C1B(4,  a0, a2, "12"); C1B(5,  a1, a3, "12");
    C1B(6,  a2, a0, "12"); C1B(7,  a3, a1, "12");
    C1B(8,  a0, a2, "12"); C1B(9,  a1, a3, "12");
    C1B(10, a2, a0, "12"); C1B(11, a3, a1, "12");
    C1B(12, a0, a2, "12"); C1B(13, a1, a3, "12");
    C1B(14, a2, a0, "12"); C1B(15, a3, a1, "12");
    C1B(16, a0, a2, "12"); C1B(17, a1, a3, "12");
    C1B(18, a2, a0, "8");  C1B(19, a3, a1, "0");
#undef C1B

    __builtin_amdgcn_s_barrier();   // all waves done with step(19) (reads buf1)

    // ---- Q2 store (ct 4-7): lane-major frag layout, f32x4 stores
    {
        float* qf = g_Q2 + (size_t)blockIdx.x * 8192 + (size_t)t * 32;
        #pragma unroll
        for (int rt = 0; rt < 2; ++rt)
            #pragma unroll
            for (int c2 = 0; c2 < 4; ++c2)
                *(f32x4*)(qf + rt * 16 + c2 * 4) = acc[rt][4 + c2];
    }

    // ---- h = relu(acc + b1 + P_r + P_c + rot tail) -> frag LDS (overlay)
    u16* hreg = smW;
    #pragma unroll
    for (int rt = 0; rt < 2; ++rt)
        #pragma unroll
        for (int ct = 0; ct < 4; ++ct)
            #pragma unroll
            for (int i = 0; i < 4; ++i) {
                const int rl = wid * 32 + rt * 16 + 4 * q + i;
                const int col = ct * 16 + n;
                float v = acc[rt][ct][i] + b1s[col]
                        + g_P[(size_t)srow[rl] * 128 + col]
                        + g_P[(size_t)scol[rl] * 128 + 64 + col]
                        + rot[rl * 4 + 0] * wtl[0 * 64 + col]
                        + rot[rl * 4 + 1] * wtl[1 * 64 + col]
                        + rot[rl * 4 + 2] * wtl[2 * 64 + col]
                        + rot[rl * 4 + 3] * wtl[3 * 64 + col];
                v = fmaxf(v, 0.f);
                unsigned int hb = __float_as_uint(v) & 0xFFFF0000u;
                const u16 hh = (u16)(hb >> 16);
                const u16 hl = f2b(v - __uint_as_float(hb));
                const int off = wid * 4096
                              + (((ct >> 1) * 2 + rt) * 64 + (n >> 2) * 16 + 4 * q + i) * 8
                              + (ct & 1) * 4 + (n & 3);
                hreg[off]        = hh;
                hreg[off + 2048] = hl;
            }

    // ---- second GEMM: o = h @ w2 + b2 (wp2 at u16 24576 hi / 28672 lo)
    f32x4 oacc[2][4];
    #pragma unroll
    for (int rt = 0; rt < 2; ++rt)
        #pragma unroll
        for (int ct = 0; ct < 4; ++ct) {
            const float bb = b2s[ct * 16 + n];
            oacc[rt][ct] = (f32x4){bb, bb, bb, bb};
        }
    #pragma unroll
    for (int kt = 0; kt < 2; ++kt) {
        const int r0 = wid * 4096 + ((kt * 2 + 0) * 64 + lane) * 8;
        const int r1 = wid * 4096 + ((kt * 2 + 1) * 64 + lane) * 8;
        bf16x8 ah0 = *(const bf16x8*)&hreg[r0];
        bf16x8 ah1 = *(const bf16x8*)&hreg[r1];
        bf16x8 al0 = *(const bf16x8*)&hreg[r0 + 2048];
        bf16x8 al1 = *(const bf16x8*)&hreg[r1 + 2048];
        #pragma unroll
        for (int ct = 0; ct < 4; ++ct) {
            bf16x8 bh = *(const bf16x8*)&smW[24576 + (kt * 4 + ct) * 512 + lane * 8];
            bf16x8 bl = *(const bf16x8*)&smW[28672 + (kt * 4 + ct) * 512 + lane * 8];
            MFMA16(ah0, bh, oacc[0][ct]);
            MFMA16(ah1, bh, oacc[1][ct]);
            MFMA16(al0, bh, oacc[0][ct]);
            MFMA16(al1, bh, oacc[1][ct]);
            MFMA16(ah0, bl, oacc[0][ct]);
            MFMA16(ah1, bl, oacc[1][ct]);
        }
    }

    // ---- scatter (pre-relu) + frag-store ex1
    #pragma unroll
    for (int rt = 0; rt < 2; ++rt)
        #pragma unroll
        for (int ct = 0; ct < 4; ++ct)
            #pragma unroll
            for (int i = 0; i < 4; ++i) {
                const int rl = wid * 32 + rt * 16 + 4 * q + i;
                atomicAdd(&g_acc[(size_t)srow[rl] * 64 + ct * 16 + n], oacc[rt][ct][i]);
            }
    frag_store_o(hreg, wid, lane, oacc, g_fragA, blockIdx.x);
}

__global__ void __launch_bounds__(256, 2) edge_c1(
        const void* efa, const void* rotsrc,
        const void* w1, const void* b1, const void* b2) {
    __shared__ __align__(16) u16 smW[32768];   // 64 KB
    __shared__ int srow[128], scol[128];
    __shared__ float b1s[64], b2s[64], rot[512], wtl[256];
    if (g_mode == 0)
        edge_c1_body<u16, u16>(smW, srow, scol, b1s, b2s, rot, wtl,
            (const u16*)efa, (const u16*)rotsrc,
            (const u16*)w1, (const u16*)b1, (const u16*)b2);
    else
        edge_c1_body<float, float>(smW, srow, scol, b1s, b2s, rot, wtl,
            (const float*)efa, (const float*)rotsrc,
            (const float*)w1, (const float*)b1, (const float*)b2);
}

// --- conv2/3/4: A from global frag buffers; W staged ONCE to LDS ------------
// Unified 48KB smW layout: [hreg 32KB (wpA overlaid at [0,NSF*16KB))]
// [wp2 16KB at byte 32768]. hreg reuses wpA after the post-K-loop barrier.
// P-gather prefetched into registers before the K-loop.
template<typename TW, int NSF, bool HASQ2, bool FRAG_OUT>
__device__ void edge_lite_body(u16* smW, int* srow, int* scol,
        float* b1s, float* b2s,
        const u16* f0, const u16* f1,
        const TW* b1v, const TW* b2v, u16* Ffrag, float* fout,
        int wpAoff, int wp2off) {
    const int t = threadIdx.x;
    const int lane = t & 63, wid = t >> 6;
    const int q = lane >> 4, n = lane & 15;
    const int e0 = blockIdx.x * 128;
    const size_t blkb = (size_t)blockIdx.x * 16384;
    constexpr int N2 = 16384;                   // u16 offset of wp2_hi in smW

    // stage wpA -> bytes [0, NSF*16K), wp2 -> bytes [32K, 48K)
    #pragma unroll
    for (int i = 0; i < (NSF + 1) * 4; ++i) {
        const int j = i * 4 + wid;              // 1KB chunk id
        const char* src;
        int dstB;
        if (j < NSF * 8) {
            src = (const char*)(g_wpA_hi + wpAoff) + j * 1024;            dstB = j * 1024;
        } else if (j < NSF * 16) {
            src = (const char*)(g_wpA_lo + wpAoff) + (j - NSF * 8) * 1024; dstB = j * 1024;
        } else if (j < NSF * 16 + 8) {
            src = (const char*)(g_wp2_hi + wp2off) + (j - NSF * 16) * 1024;
            dstB = 32768 + (j - NSF * 16) * 1024;
        } else {
            src = (const char*)(g_wp2_lo + wp2off) + (j - NSF * 16 - 8) * 1024;
            dstB = 32768 + (j - NSF * 16) * 1024;
        }
        gl_lds16(src + lane * 16, (char*)smW + dstB);
    }

    if (t < 128) srow[t] = g_row[e0 + t];
    else         scol[t - 128] = g_col[e0 + t - 128];
    if (t >= 128 && t < 192) b1s[t - 128] = ldf(b1v + (t - 128));
    if (t >= 192)            b2s[t - 192] = ldf(b2v + (t - 192));
    __syncthreads();          // drains staging (vmcnt0) + prologue, one-time

    // ---- prefetch P-gather into registers (overlaps the frag K-loop)
    float pr[2][4][4], pc[2][4][4];
    #pragma unroll
    for (int rt = 0; rt < 2; ++rt)
        #pragma unroll
        for (int ct = 0; ct < 4; ++ct)
            #pragma unroll
            for (int i = 0; i < 4; ++i) {
                const int rl = wid * 32 + rt * 16 + 4 * q + i;
                const int col = ct * 16 + n;
                pr[rt][ct][i] = g_P[(size_t)srow[rl] * 128 + col];
                pc[rt][ct][i] = g_P[(size_t)scol[rl] * 128 + 64 + col];
            }

    f32x4 acc[2][4];
    #pragma unroll
    for (int a_ = 0; a_ < 2; ++a_)
        #pragma unroll
        for (int b_ = 0; b_ < 4; ++b_)
            acc[a_][b_] = (f32x4){0.f, 0.f, 0.f, 0.f};

    #pragma unroll
    for (int s = 0; s < NSF; ++s) {
        const u16* fs = (s == 0) ? f0 : f1;
        #pragma unroll
        for (int kt = 0; kt < 2; ++kt) {
            const size_t ba0 = blkb + (size_t)(kt * 8 + wid * 2 + 0) * 512 + lane * 8;
            const size_t ba1 = blkb + (size_t)(kt * 8 + wid * 2 + 1) * 512 + lane * 8;
            bf16x8 ah0 = *(const bf16x8*)&fs[ba0];
            bf16x8 al0 = *(const bf16x8*)&fs[ba0 + 8192];
            bf16x8 ah1 = *(const bf16x8*)&fs[ba1];
            bf16x8 al1 = *(const bf16x8*)&fs[ba1 + 8192];
            #pragma unroll
            for (int ct = 0; ct < 4; ++ct) {
                bf16x8 bh = *(const bf16x8*)&smW[s * 4096 + (kt * 4 + ct) * 512 + lane * 8];
                bf16x8 bl = *(const bf16x8*)&smW[NSF * 4096 + s * 4096 + (kt * 4 + ct) * 512 + lane * 8];
                MFMA16(ah0, bh, acc[0][ct]);
                MFMA16(ah1, bh, acc[1][ct]);
                MFMA16(al0, bh, acc[0][ct]);
                MFMA16(al1, bh, acc[1][ct]);
                MFMA16(ah0, bl, acc[0][ct]);
                MFMA16(ah1, bl, acc[1][ct]);
            }
        }
    }

    __builtin_amdgcn_s_barrier();   // all waves done reading wpA (hreg reuses it)
    u16* hreg = smW;

    const float* qf = g_Q2 + (size_t)blockIdx.x * 8192 + (size_t)t * 32;
    #pragma unroll
    for (int rt = 0; rt < 2; ++rt)
        #pragma unroll
        for (int ct = 0; ct < 4; ++ct) {
            f32x4 qv;
            if constexpr (HASQ2) qv = *(const f32x4*)(qf + rt * 16 + ct * 4);
            #pragma unroll
            for (int i = 0; i < 4; ++i) {
                const int rl = wid * 32 + rt * 16 + 4 * q + i;
                const int col = ct * 16 + n;
                float v = acc[rt][ct][i] + b1s[col]
                        + pr[rt][ct][i] + pc[rt][ct][i];
                if constexpr (HASQ2) v += qv[i];
                v = fmaxf(v, 0.f);
                unsigned int hb = __float_as_uint(v) & 0xFFFF0000u;
                const u16 hh = (u16)(hb >> 16);
                const u16 hl = f2b(v - __uint_as_float(hb));
                const int off = wid * 4096
                              + (((ct >> 1) * 2 + rt) * 64 + (n >> 2) * 16 + 4 * q + i) * 8
                              + (ct & 1) * 4 + (n & 3);
                hreg[off]        = hh;
                hreg[off + 2048] = hl;
            }
        }

    f32x4 oacc[2][4];
    #pragma unroll
    for (int rt = 0; rt < 2; ++rt)
        #pragma unroll
        for (int ct = 0; ct < 4; ++ct) {
            const float bb = b2s[ct * 16 + n];
            oacc[rt][ct] = (f32x4){bb, bb, bb, bb};
        }
    #pragma unroll
    for (int kt = 0; kt < 2; ++kt) {
        const int r0 = wid * 4096 + ((kt * 2 + 0) * 64 + lane) * 8;
        const int r1 = wid * 4096 + ((kt * 2 + 1) * 64 + lane) * 8;
        bf16x8 ah0 = *(const bf16x8*)&hreg[r0];
        bf16x8 ah1 = *(const bf16x8*)&hreg[r1];
        bf16x8 al0 = *(const bf16x8*)&hreg[r0 + 2048];
        bf16x8 al1 = *(const bf16x8*)&hreg[r1 + 2048];
        #pragma unroll
        for (int ct = 0; ct < 4; ++ct) {
            bf16x8 bh = *(const bf16x8*)&smW[N2 + (kt * 4 + ct) * 512 + lane * 8];
            bf16x8 bl = *(const bf16x8*)&smW[N2 + 4096 + (kt * 4 + ct) * 512 + lane * 8];
            MFMA16(ah0, bh, oacc[0][ct]);
            MFMA16(ah1, bh, oacc[1][ct]);
            MFMA16(al0, bh, oacc[0][ct]);
            MFMA16(al1, bh, oacc[1][ct]);
            MFMA16(ah0, bl, oacc[0][ct]);
            MFMA16(ah1, bl, oacc[1][ct]);
        }
    }

    #pragma unroll
    for (int rt = 0; rt < 2; ++rt)
        #pragma unroll
        for (int ct = 0; ct < 4; ++ct)
            #pragma unroll
            for (int i = 0; i < 4; ++i) {
                const int rl = wid * 32 + rt * 16 + 4 * q + i;
                const int col = ct * 16 + n;
                const float v = oacc[rt][ct][i];
                atomicAdd(&g_acc[(size_t)srow[rl] * 64 + col], v);
                if constexpr (!FRAG_OUT)
                    fout[(size_t)(e0 + rl) * 64 + col] = v;   // ex4: pre-relu f32
            }
    if constexpr (FRAG_OUT)
        frag_store_o(hreg, wid, lane, oacc, Ffrag, blockIdx.x);
}

template<int NSF, bool HASQ2, bool FRAG_OUT>
__global__ void __launch_bounds__(256, 3) edge_lite(
        const u16* f0, const u16* f1, const void* b1, const void* b2,
        u16* Ffrag, float* fout, int wpAoff, int wp2off) {
    __shared__ __align__(16) u16 smW[24576];
    __shared__ int srow[128], scol[128];
    __shared__ float b1s[64], b2s[64];
    if (g_mode == 0)
        edge_lite_body<u16, NSF, HASQ2, FRAG_OUT>(smW, srow, scol, b1s, b2s,
            f0, f1, (const u16*)b1, (const u16*)b2, Ffrag, fout, wpAoff, wp2off);
    else
        edge_lite_body<float, NSF, HASQ2, FRAG_OUT>(smW, srow, scol, b1s, b2s,
            f0, f1, (const float*)b1, (const float*)b2, Ffrag, fout, wpAoff, wp2off);
}

// --- tail: blocks [0,2500) final_node ; [2500,2750) edge_head ---------------
template<typename T>
__device__ void final_node_body(const T* w, const T* b, T* out, int bid) {
    const int t = threadIdx.x;
    const int lane = t & 63;
    const int n = bid * 4 + (t >> 6);
    float inv = 1.0f / fmaxf(g_deg[n], 1.0f);
    float x4 = fmaxf(g_acc[(size_t)n * 64 + lane] * inv, 0.0f);
    float r[4];
    #pragma unroll
    for (int j = 0; j < 4; ++j) {
        float v = x4 * ldf(w + lane * 4 + j);
        #pragma unroll
        for (int off = 32; off >= 1; off >>= 1) v += __shfl_xor(v, off);
        r[j] = v + ldf(b + j);
    }
    float nrm = sqrtf(r[0]*r[0] + r[1]*r[1] + r[2]*r[2] + r[3]*r[3]);
    float dn = fmaxf(nrm, 1e-12f);
    if (lane < 4) stf(out + n * 4 + lane, r[lane] / dn);
}

template<typename T>
__device__ void edge_head_body(const float* ex4, const T* w1, const T* b1,
                               const T* w2, const T* b2, T* out, int bid) {
    __shared__ float lw1[2048];
    __shared__ float lw2[32];
    const int t = threadIdx.x;
    for (int i = t; i < 2048; i += 256) lw1[i] = ldf(w1 + i);
    if (t < 32) lw2[t] = ldf(w2 + t);
    __syncthreads();
    const int e = bid * 256 + t;                  // exact: 250*256 = 64000
    float a[32];
    #pragma unroll
    for (int j = 0; j < 32; ++j) a[j] = ldf(b1 + j);
    const float* p0 = ex4 + (size_t)e * 64;
    const float* p1 = ex4 + (size_t)(e + E_HALF) * 64;
    for (int c = 0; c < 64; ++c) {
        float h = p0[c] + p1[c];
        #pragma unroll
        for (int j = 0; j < 32; ++j) a[j] += h * lw1[c * 32 + j];
    }
    float s = ldf(b2);
    #pragma unroll
    for (int j = 0; j < 32; ++j) s += fmaxf(a[j], 0.f) * lw2[j];
    stf(out + e, s);
}

__global__ void __launch_bounds__(256) tail_k(
        const void* lw, const void* lb, const float* ex4,
        const void* ew1, const void* eb1, const void* ew2, const void* eb2,
        void* out) {
    const int b = blockIdx.x;
    if (b < 2500) {
        if (g_mode == 0) final_node_body<u16>((const u16*)lw, (const u16*)lb, (u16*)out, b);
        else             final_node_body<float>((const float*)lw, (const float*)lb, (float*)out, b);
    } else {
        if (g_mode == 0)
            edge_head_body<u16>(ex4, (const u16*)ew1, (const u16*)eb1,
                (const u16*)ew2, (const u16*)eb2, (u16*)out + 40000, b - 2500);
        else
            edge_head_body<float>(ex4, (const float*)ew1, (const float*)eb1,
                (const float*)ew2, (const float*)eb2, (float*)out + 40000, b - 2500);
    }
}

// --- layout tripwire: fill out with ~996.5 pattern --------------------------
__global__ void sentinel_fill(unsigned int* out, int n_words) {
    int i = blockIdx.x * 256 + threadIdx.x;
    if (i < n_words) out[i] = 0x44794479u;
}

static void* sym_addr(const void* symbol) {
    void* p = nullptr;
    (void)hipGetSymbolAddress(&p, symbol);
    return p;
}

extern "C" void kernel_launch(void* const* d_in, const int* in_sizes, int n_in,
                              void* d_out, int out_size, void* d_ws, size_t ws_size,
                              hipStream_t stream) {
    (void)d_ws; (void)ws_size;
    bool ok = (n_in == 27) && (out_size == 104000)
           && (in_sizes[0] == 2560000) && (in_sizes[2] == 256000)
           && (in_sizes[3] == 81920000) && (in_sizes[5] == 74496)
           && (in_sizes[21] == 256) && (in_sizes[25] == 32);
    if (!ok) {   // wrong layout assumption -> recognizable absmax ~996
        sentinel_fill<<<204, 256, 0, stream>>>((unsigned int*)d_out, 52000);
        return;
    }
    const void* x_org     = d_in[0];
    const void* x_rot     = d_in[1];
    const int*  eidx      = (const int*)d_in[2];
    const void* edge_attr = d_in[3];
    const void* edge_rot  = d_in[4];

    float* P   = (float*)sym_addr(HIP_SYMBOL(g_P));
    float* x1  = (float*)sym_addr(HIP_SYMBOL(g_x1));
    float* x2  = (float*)sym_addr(HIP_SYMBOL(g_x2));
    float* x3  = (float*)sym_addr(HIP_SYMBOL(g_x3));
    u16*   fA  = (u16*)sym_addr(HIP_SYMBOL(g_fragA));
    u16*   fB  = (u16*)sym_addr(HIP_SYMBOL(g_fragB));
    float* ex4 = (float*)sym_addr(HIP_SYMBOL(g_ex4));

    // 1. zero acc/deg + dtype/idx detect
    prologue_a<<<2500, 256, 0, stream>>>(x_org, eidx);
    // 2. all weight packs (752 blocks) + idx convert + degree (500 blocks)
    prep_k<<<1252, 256, 0, stream>>>(d_in[5], d_in[7], d_in[9], d_in[11],
                                     d_in[13], d_in[15], d_in[17], d_in[19], eidx);

    // conv1 (+fused Q2 for conv2)
    node_mfma_in<<<157, 256, 0, stream>>>(x_org, x_rot, d_in[5], P);
    edge_c1<<<NBLK, 256, 0, stream>>>(edge_attr, edge_rot, d_in[5], d_in[6], d_in[8]);

    // conv2: node GEMM fused with x1 = acc/deg (no relu), zero acc
    node_mfma_acc<0, false><<<157, 256, 0, stream>>>(nullptr, x1, P, 4 * 8192);
    edge_lite<1, true, true><<<NBLK, 256, 0, stream>>>(
        fA, nullptr, d_in[10], d_in[12], fB, nullptr, 0, 4096);           // ex2

    // conv3: x2 = relu(acc/deg); A = [x2|x1]
    node_mfma_acc<1, true><<<157, 256, 0, stream>>>(x1, x2, P, 5 * 8192);
    edge_lite<2, false, true><<<NBLK, 256, 0, stream>>>(
        fB, fA, d_in[14], d_in[16], fA, nullptr, 4096, 8192);             // ex3 over ex1
    // conv4: x3 = relu(acc/deg); A = [x3|x2]
    node_mfma_acc<1, true><<<157, 256, 0, stream>>>(x2, x3, P, 7 * 8192);
    edge_lite<2, false, false><<<NBLK, 256, 0, stream>>>(
        fA, fB, d_in[18], d_in[20], nullptr, ex4, 12288, 12288);          // ex4

    // x4 -> lin1 -> normalize (reads g_acc directly) + edge head
    tail_k<<<2750, 256, 0, stream>>>(d_in[21], d_in[22], ex4,
                                     d_in[23], d_in[24], d_in[25], d_in[26], d_out);
}